// Round 1
// baseline (8390.185 us; speedup 1.0000x reference)
//
#include <hip/hip_runtime.h>

#define NN 100000
#define NE 1600000
#define D  128
#define NG 128
#define NO 16

// ---------------- utility ----------------
__global__ void k_zero(float* __restrict__ p, int n4) {
  int i = blockIdx.x * blockDim.x + threadIdx.x;
  float4 z = make_float4(0.f, 0.f, 0.f, 0.f);
  for (; i < n4; i += gridDim.x * blockDim.x) ((float4*)p)[i] = z;
}

__global__ void k_deg(const int* __restrict__ dst, float* __restrict__ deg) {
  int e = blockIdx.x * blockDim.x + threadIdx.x;
  if (e < NE) unsafeAtomicAdd(&deg[dst[e]], 1.0f);
}

__global__ void k_inv(const float* __restrict__ deg, float* __restrict__ inv) {
  int i = blockIdx.x * blockDim.x + threadIdx.x;
  if (i < NN) inv[i] = 1.0f / (deg[i] + 1.0f);
}

// ---------------- edge scatter: agg[dst] += h[src] ----------------
// 32 threads per edge, each thread handles one float4 (4 atomics)
__global__ void k_scatter(const float* __restrict__ h, const int* __restrict__ src,
                          const int* __restrict__ dst, float* __restrict__ agg) {
  int t = blockIdx.x * 256 + threadIdx.x;
  int e = t >> 5;
  int l = t & 31;
  if (e >= NE) return;
  int s = src[e], d = dst[e];
  float4 v = ((const float4*)(h + (size_t)s * D))[l];
  float* o = agg + (size_t)d * D + l * 4;
  unsafeAtomicAdd(o + 0, v.x);
  unsafeAtomicAdd(o + 1, v.y);
  unsafeAtomicAdd(o + 2, v.z);
  unsafeAtomicAdd(o + 3, v.w);
}

// ---------------- fused norm + dense: out = act(((agg+h)*inv) @ W + b) ----------------
// block: 256 threads, 64 nodes x 128 cols output tile.
// thread (tx = t&15 -> 8 cols, ty = t>>4 -> 4 nodes), acc[4][8].
// K staged in chunks of 32 (W chunk 16KB + norm tile ~9KB in LDS).
// out may alias agg: each block reads only its own 64 rows of agg (all reads
// happen in the staging loop) and writes only its own rows in the epilogue.
#define NT 64
#define KC 32

template <int RELU>
__global__ __launch_bounds__(256) void k_linear(
    const float* __restrict__ agg, const float* __restrict__ h,
    const float* __restrict__ inv, const float* __restrict__ W,
    const float* __restrict__ b, float* __restrict__ out) {
  __shared__ float sN[NT][KC + 4];   // stride 36 floats (16B-aligned rows)
  __shared__ float sW[KC][D];

  int t = threadIdx.x;
  int base = blockIdx.x * NT;
  int tx = t & 15;
  int ty = t >> 4;
  int tx8 = tx * 8;
  int ty4 = ty * 4;

  float acc[4][8];
#pragma unroll
  for (int i = 0; i < 4; i++)
#pragma unroll
    for (int j = 0; j < 8; j++) acc[i][j] = 0.f;

  for (int kc = 0; kc < D; kc += KC) {
    // stage norm tile: 64 nodes x 32 k = 512 float4, 2 per thread
#pragma unroll
    for (int r = 0; r < 2; r++) {
      int q = t + 256 * r;
      int nl = q >> 3;          // node local 0..63
      int kq = (q & 7) * 4;     // k offset within chunk
      int n = base + nl;
      float4 v = make_float4(0.f, 0.f, 0.f, 0.f);
      if (n < NN) {
        size_t off = (size_t)n * D + kc + kq;
        float4 a = *(const float4*)(agg + off);
        float4 hh = *(const float4*)(h + off);
        float iv = inv[n];
        v.x = (a.x + hh.x) * iv;
        v.y = (a.y + hh.y) * iv;
        v.z = (a.z + hh.z) * iv;
        v.w = (a.w + hh.w) * iv;
      }
      *(float4*)&sN[nl][kq] = v;
    }
    // stage W chunk: 32 rows x 128 cols = 1024 float4, 4 per thread
#pragma unroll
    for (int r = 0; r < 4; r++) {
      int q = t + 256 * r;
      int kl = q >> 5;
      int c4 = (q & 31) * 4;
      float4 wv = *(const float4*)(W + (size_t)(kc + kl) * D + c4);
      *(float4*)&sW[kl][c4] = wv;
    }
    __syncthreads();

#pragma unroll 4
    for (int k = 0; k < KC; k++) {
      float n0 = sN[ty4 + 0][k];
      float n1 = sN[ty4 + 1][k];
      float n2 = sN[ty4 + 2][k];
      float n3 = sN[ty4 + 3][k];
      float4 w0 = *(const float4*)&sW[k][tx8];
      float4 w1 = *(const float4*)&sW[k][tx8 + 4];
      acc[0][0] += n0 * w0.x; acc[0][1] += n0 * w0.y; acc[0][2] += n0 * w0.z; acc[0][3] += n0 * w0.w;
      acc[0][4] += n0 * w1.x; acc[0][5] += n0 * w1.y; acc[0][6] += n0 * w1.z; acc[0][7] += n0 * w1.w;
      acc[1][0] += n1 * w0.x; acc[1][1] += n1 * w0.y; acc[1][2] += n1 * w0.z; acc[1][3] += n1 * w0.w;
      acc[1][4] += n1 * w1.x; acc[1][5] += n1 * w1.y; acc[1][6] += n1 * w1.z; acc[1][7] += n1 * w1.w;
      acc[2][0] += n2 * w0.x; acc[2][1] += n2 * w0.y; acc[2][2] += n2 * w0.z; acc[2][3] += n2 * w0.w;
      acc[2][4] += n2 * w1.x; acc[2][5] += n2 * w1.y; acc[2][6] += n2 * w1.z; acc[2][7] += n2 * w1.w;
      acc[3][0] += n3 * w0.x; acc[3][1] += n3 * w0.y; acc[3][2] += n3 * w0.z; acc[3][3] += n3 * w0.w;
      acc[3][4] += n3 * w1.x; acc[3][5] += n3 * w1.y; acc[3][6] += n3 * w1.z; acc[3][7] += n3 * w1.w;
    }
    __syncthreads();
  }

  // epilogue
#pragma unroll
  for (int i = 0; i < 4; i++) {
    int n = base + ty4 + i;
    if (n >= NN) continue;
    float4 o0, o1;
    o0.x = acc[i][0] + b[tx8 + 0];
    o0.y = acc[i][1] + b[tx8 + 1];
    o0.z = acc[i][2] + b[tx8 + 2];
    o0.w = acc[i][3] + b[tx8 + 3];
    o1.x = acc[i][4] + b[tx8 + 4];
    o1.y = acc[i][5] + b[tx8 + 5];
    o1.z = acc[i][6] + b[tx8 + 6];
    o1.w = acc[i][7] + b[tx8 + 7];
    if (RELU) {
      o0.x = fmaxf(o0.x, 0.f); o0.y = fmaxf(o0.y, 0.f);
      o0.z = fmaxf(o0.z, 0.f); o0.w = fmaxf(o0.w, 0.f);
      o1.x = fmaxf(o1.x, 0.f); o1.y = fmaxf(o1.y, 0.f);
      o1.z = fmaxf(o1.z, 0.f); o1.w = fmaxf(o1.w, 0.f);
    }
    *(float4*)&out[(size_t)n * D + tx8] = o0;
    *(float4*)&out[(size_t)n * D + tx8 + 4] = o1;
  }
}

// ---------------- readout: w = sigmoid(h@Wv+bv); num[g] += w*h; den[g] += w ----------------
// 128 nodes per block; graph_id is sorted -> accumulate runs, flush at boundaries.
__global__ __launch_bounds__(256) void k_readout(
    const float* __restrict__ h, const int* __restrict__ gid,
    const float* __restrict__ Wv, const float* __restrict__ bv,
    float* __restrict__ num, float* __restrict__ den) {
  __shared__ float wl[128];
  int base = blockIdx.x * 128;
  int t = threadIdx.x;

  // phase 1: gate weights (lane pairs: one node per 2 lanes)
  {
    int n = base + (t >> 1);
    int half = t & 1;
    float s = 0.f;
    if (n < NN) {
      const float4* hp = (const float4*)(h + (size_t)n * D + half * 64);
      const float4* wp = (const float4*)(Wv + half * 64);
#pragma unroll
      for (int i = 0; i < 16; i++) {
        float4 a = hp[i], w = wp[i];
        s += a.x * w.x + a.y * w.y + a.z * w.z + a.w * w.w;
      }
    }
    s += __shfl_xor(s, 1);
    if (half == 0) {
      float wv = 0.f;
      if (n < NN) wv = 1.f / (1.f + expf(-(s + bv[0])));
      wl[t >> 1] = wv;
    }
  }
  __syncthreads();

  // phase 2: segmented accumulation (sorted graph_id)
  int c = t & 127;
  int rg = t >> 7;  // 0/1 -> node rows rg*64..rg*64+63
  float acc = 0.f, wacc = 0.f;
  int cur = -1;
  for (int i = 0; i < 64; i++) {
    int nl = rg * 64 + i;
    int n = base + nl;
    if (n >= NN) break;
    int g = gid[n];
    if (g != cur) {
      if (cur >= 0) {
        unsafeAtomicAdd(&num[(size_t)cur * D + c], acc);
        if (c == 0) unsafeAtomicAdd(&den[cur], wacc);
      }
      cur = g; acc = 0.f; wacc = 0.f;
    }
    float wv = wl[nl];
    acc += wv * h[(size_t)n * D + c];
    if (c == 0) wacc += wv;
  }
  if (cur >= 0) {
    unsafeAtomicAdd(&num[(size_t)cur * D + c], acc);
    if (c == 0) unsafeAtomicAdd(&den[cur], wacc);
  }
}

// ---------------- final: out[g][o] = (num[g]/den[g]) @ Wc + bc ----------------
__global__ void k_final(const float* __restrict__ num, const float* __restrict__ den,
                        const float* __restrict__ Wc, const float* __restrict__ bc,
                        float* __restrict__ out) {
  int t = threadIdx.x;
  int o = t & 15;
  for (int g = t >> 4; g < NG; g += 16) {
    float s = 0.f;
    const float* np = num + (size_t)g * D;
#pragma unroll 8
    for (int c = 0; c < D; c++) s += np[c] * Wc[c * NO + o];
    out[g * NO + o] = s / den[g] + bc[o];
  }
}

// ---------------- launch ----------------
extern "C" void kernel_launch(void* const* d_in, const int* in_sizes, int n_in,
                              void* d_out, int out_size, void* d_ws, size_t ws_size,
                              hipStream_t stream) {
  const float* x   = (const float*)d_in[0];
  const int*   src = (const int*)d_in[1];
  const int*   dst = (const int*)d_in[2];
  const int*   gid = (const int*)d_in[3];
  const float* W1  = (const float*)d_in[4];
  const float* b1  = (const float*)d_in[5];
  const float* W2  = (const float*)d_in[6];
  const float* b2  = (const float*)d_in[7];
  const float* W3  = (const float*)d_in[8];
  const float* b3  = (const float*)d_in[9];
  const float* Wv  = (const float*)d_in[10];
  const float* bv  = (const float*)d_in[11];
  const float* Wc  = (const float*)d_in[12];
  const float* bc  = (const float*)d_in[13];
  float* out = (float*)d_out;

  float* ws   = (float*)d_ws;
  float* bufA = ws;                    // 12,800,000 floats
  float* bufB = ws + 12800000;         // 12,800,000 floats
  float* inv  = ws + 25600000;         // 100,000
  float* deg  = ws + 25700000;         // 100,000
  float* num  = ws + 25800000;         // 16,384
  float* den  = ws + 25816384;         // 128

  // degree + inverse
  k_zero<<<98, 256, 0, stream>>>(deg, 25000);
  k_deg<<<6250, 256, 0, stream>>>(dst, deg);
  k_inv<<<391, 256, 0, stream>>>(deg, inv);

  // layer 1: x -> bufA
  k_zero<<<2048, 256, 0, stream>>>(bufA, 3200000);
  k_scatter<<<200000, 256, 0, stream>>>(x, src, dst, bufA);
  k_linear<1><<<1563, 256, 0, stream>>>(bufA, x, inv, W1, b1, bufA);

  // layer 2: bufA -> bufB
  k_zero<<<2048, 256, 0, stream>>>(bufB, 3200000);
  k_scatter<<<200000, 256, 0, stream>>>(bufA, src, dst, bufB);
  k_linear<1><<<1563, 256, 0, stream>>>(bufB, bufA, inv, W2, b2, bufB);

  // layer 3: bufB -> bufA
  k_zero<<<2048, 256, 0, stream>>>(bufA, 3200000);
  k_scatter<<<200000, 256, 0, stream>>>(bufB, src, dst, bufA);
  k_linear<0><<<1563, 256, 0, stream>>>(bufA, bufB, inv, W3, b3, bufA);

  // readout
  k_zero<<<17, 256, 0, stream>>>(num, 4128);  // num (16384) + den (128) contiguous
  k_readout<<<782, 256, 0, stream>>>(bufA, gid, Wv, bv, num, den);
  k_final<<<1, 256, 0, stream>>>(num, den, Wc, bc, out);
}

// Round 2
// 1390.624 us; speedup vs baseline: 6.0334x; 6.0334x over previous
//
#include <hip/hip_runtime.h>

#define NN 100000
#define NE 1600000
#define D  128
#define NG 128
#define NO 16

// ---------------- utility ----------------
__global__ void k_zero(float* __restrict__ p, int n4) {
  int i = blockIdx.x * blockDim.x + threadIdx.x;
  float4 z = make_float4(0.f, 0.f, 0.f, 0.f);
  for (; i < n4; i += gridDim.x * blockDim.x) ((float4*)p)[i] = z;
}

// count in-degree into fill[] (int atomics)
__global__ void k_count(const int* __restrict__ dst, int* __restrict__ cnt) {
  int e = blockIdx.x * blockDim.x + threadIdx.x;
  if (e < NE) atomicAdd(&cnt[dst[e]], 1);
}

// single-block exclusive scan of cnt -> row_ptr, and inv = 1/(deg+1)
__global__ __launch_bounds__(1024) void k_scan(const int* __restrict__ cnt,
                                               int* __restrict__ row_ptr,
                                               float* __restrict__ inv) {
  __shared__ int s[1024];
  const int CH = 98;  // 1024*98 = 100352 >= NN
  int t = threadIdx.x;
  int lo = t * CH;
  int hi = lo + CH; if (hi > NN) hi = NN;
  int sum = 0;
  for (int i = lo; i < hi && i < NN; i++) sum += cnt[i];
  s[t] = sum;
  __syncthreads();
  for (int d = 1; d < 1024; d <<= 1) {
    int x = (t >= d) ? s[t - d] : 0;
    __syncthreads();
    s[t] += x;
    __syncthreads();
  }
  int excl = s[t] - sum;
  int run = excl;
  for (int i = lo; i < hi && i < NN; i++) {
    row_ptr[i] = run;
    int c = cnt[i];
    inv[i] = 1.0f / (float)(c + 1);
    run += c;
  }
  if (t == 1023) row_ptr[NN] = excl;  // empty chunk -> excl == NE
}

// fill CSR: eidx[row_ptr[d] + k] = src[e]
__global__ void k_fill(const int* __restrict__ src, const int* __restrict__ dst,
                       const int* __restrict__ row_ptr, int* __restrict__ fill,
                       int* __restrict__ eidx) {
  int e = blockIdx.x * blockDim.x + threadIdx.x;
  if (e >= NE) return;
  int d = dst[e];
  int k = atomicAdd(&fill[d], 1);
  eidx[row_ptr[d] + k] = src[e];
}

// ---------------- fused layer: out = act(((gather+self)*inv) @ W + b) ----------------
// block = 256 threads, 64 nodes. Phase 1: gather node rows (CSR) + normalize
// into LDS sN[64][132]. Phase 2: GEMM vs W (staged in 32-row chunks).
// out must NOT alias h (gathers read random rows of h).
template <int RELU>
__global__ __launch_bounds__(256) void k_layer(
    const float* __restrict__ h, const int* __restrict__ rp,
    const int* __restrict__ eidx, const float* __restrict__ inv,
    const float* __restrict__ W, const float* __restrict__ b,
    float* __restrict__ out) {
  __shared__ float sN[64][132];  // +4 pad: GEMM row reads become 2-way (free)
  __shared__ float sW[32][128];

  int t = threadIdx.x;
  int base = blockIdx.x * 64;
  const float4* h4 = (const float4*)h;

  // ---- phase 1: gather. 8 groups of 32 lanes; each group does one node/iter.
  {
    int l = t & 31;   // float4 column
    int g = t >> 5;   // group 0..7
    for (int it = 0; it < 8; ++it) {
      int nl = it * 8 + g;
      int n = base + nl;
      float4 acc = make_float4(0.f, 0.f, 0.f, 0.f);
      if (n < NN) {
        int s0 = rp[n], s1 = rp[n + 1];
        for (int i = s0; i < s1; i++) {
          int u = eidx[i];
          float4 v = h4[u * 32 + l];
          acc.x += v.x; acc.y += v.y; acc.z += v.z; acc.w += v.w;
        }
        float4 self = h4[n * 32 + l];
        float iv = inv[n];
        acc.x = (acc.x + self.x) * iv;
        acc.y = (acc.y + self.y) * iv;
        acc.z = (acc.z + self.z) * iv;
        acc.w = (acc.w + self.w) * iv;
      }
      *(float4*)&sN[nl][l * 4] = acc;
    }
  }
  __syncthreads();

  // ---- phase 2: GEMM. thread (tx=t&15, ty=t>>4): 4 nodes x cols {tx*4, tx*4+64}
  int tx = t & 15;
  int ty = t >> 4;
  int c0 = tx * 4;
  int c1 = tx * 4 + 64;
  int ty4 = ty * 4;

  float acc[4][8];
#pragma unroll
  for (int i = 0; i < 4; i++)
#pragma unroll
    for (int j = 0; j < 8; j++) acc[i][j] = 0.f;

  for (int kc = 0; kc < D; kc += 32) {
    // stage W chunk: 32 rows x 128 cols = 1024 float4, 4 per thread
#pragma unroll
    for (int r = 0; r < 4; r++) {
      int q = t + 256 * r;
      int kl = q >> 5;
      int c4 = (q & 31) * 4;
      *(float4*)&sW[kl][c4] = *(const float4*)(W + (size_t)(kc + kl) * D + c4);
    }
    __syncthreads();

#pragma unroll 4
    for (int k = 0; k < 32; k++) {
      int kk = kc + k;
      float n0 = sN[ty4 + 0][kk];
      float n1 = sN[ty4 + 1][kk];
      float n2 = sN[ty4 + 2][kk];
      float n3 = sN[ty4 + 3][kk];
      float4 w0 = *(const float4*)&sW[k][c0];
      float4 w1 = *(const float4*)&sW[k][c1];
      acc[0][0] += n0 * w0.x; acc[0][1] += n0 * w0.y; acc[0][2] += n0 * w0.z; acc[0][3] += n0 * w0.w;
      acc[0][4] += n0 * w1.x; acc[0][5] += n0 * w1.y; acc[0][6] += n0 * w1.z; acc[0][7] += n0 * w1.w;
      acc[1][0] += n1 * w0.x; acc[1][1] += n1 * w0.y; acc[1][2] += n1 * w0.z; acc[1][3] += n1 * w0.w;
      acc[1][4] += n1 * w1.x; acc[1][5] += n1 * w1.y; acc[1][6] += n1 * w1.z; acc[1][7] += n1 * w1.w;
      acc[2][0] += n2 * w0.x; acc[2][1] += n2 * w0.y; acc[2][2] += n2 * w0.z; acc[2][3] += n2 * w0.w;
      acc[2][4] += n2 * w1.x; acc[2][5] += n2 * w1.y; acc[2][6] += n2 * w1.z; acc[2][7] += n2 * w1.w;
      acc[3][0] += n3 * w0.x; acc[3][1] += n3 * w0.y; acc[3][2] += n3 * w0.z; acc[3][3] += n3 * w0.w;
      acc[3][4] += n3 * w1.x; acc[3][5] += n3 * w1.y; acc[3][6] += n3 * w1.z; acc[3][7] += n3 * w1.w;
    }
    __syncthreads();
  }

  // epilogue
#pragma unroll
  for (int i = 0; i < 4; i++) {
    int n = base + ty4 + i;
    if (n >= NN) continue;
    float4 o0, o1;
    o0.x = acc[i][0] + b[c0 + 0];
    o0.y = acc[i][1] + b[c0 + 1];
    o0.z = acc[i][2] + b[c0 + 2];
    o0.w = acc[i][3] + b[c0 + 3];
    o1.x = acc[i][4] + b[c1 + 0];
    o1.y = acc[i][5] + b[c1 + 1];
    o1.z = acc[i][6] + b[c1 + 2];
    o1.w = acc[i][7] + b[c1 + 3];
    if (RELU) {
      o0.x = fmaxf(o0.x, 0.f); o0.y = fmaxf(o0.y, 0.f);
      o0.z = fmaxf(o0.z, 0.f); o0.w = fmaxf(o0.w, 0.f);
      o1.x = fmaxf(o1.x, 0.f); o1.y = fmaxf(o1.y, 0.f);
      o1.z = fmaxf(o1.z, 0.f); o1.w = fmaxf(o1.w, 0.f);
    }
    *(float4*)&out[(size_t)n * D + c0] = o0;
    *(float4*)&out[(size_t)n * D + c1] = o1;
  }
}

// ---------------- readout: w = sigmoid(h@Wv+bv); num[g] += w*h; den[g] += w ----------------
__global__ __launch_bounds__(256) void k_readout(
    const float* __restrict__ h, const int* __restrict__ gid,
    const float* __restrict__ Wv, const float* __restrict__ bv,
    float* __restrict__ num, float* __restrict__ den) {
  __shared__ float wl[128];
  int base = blockIdx.x * 128;
  int t = threadIdx.x;

  // phase 1: gate weights (one node per 2 lanes)
  {
    int n = base + (t >> 1);
    int half = t & 1;
    float s = 0.f;
    if (n < NN) {
      const float4* hp = (const float4*)(h + (size_t)n * D + half * 64);
      const float4* wp = (const float4*)(Wv + half * 64);
#pragma unroll
      for (int i = 0; i < 16; i++) {
        float4 a = hp[i], w = wp[i];
        s += a.x * w.x + a.y * w.y + a.z * w.z + a.w * w.w;
      }
    }
    s += __shfl_xor(s, 1);
    if (half == 0) {
      float wv = 0.f;
      if (n < NN) wv = 1.f / (1.f + expf(-(s + bv[0])));
      wl[t >> 1] = wv;
    }
  }
  __syncthreads();

  // phase 2: segmented accumulation (graph_id sorted)
  int c = t & 127;
  int rg = t >> 7;
  float acc = 0.f, wacc = 0.f;
  int cur = -1;
  for (int i = 0; i < 64; i++) {
    int nl = rg * 64 + i;
    int n = base + nl;
    if (n >= NN) break;
    int g = gid[n];
    if (g != cur) {
      if (cur >= 0) {
        unsafeAtomicAdd(&num[(size_t)cur * D + c], acc);
        if (c == 0) unsafeAtomicAdd(&den[cur], wacc);
      }
      cur = g; acc = 0.f; wacc = 0.f;
    }
    float wv = wl[nl];
    acc += wv * h[(size_t)n * D + c];
    if (c == 0) wacc += wv;
  }
  if (cur >= 0) {
    unsafeAtomicAdd(&num[(size_t)cur * D + c], acc);
    if (c == 0) unsafeAtomicAdd(&den[cur], wacc);
  }
}

// ---------------- final: out[g][o] = (num[g]/den[g]) @ Wc + bc ----------------
__global__ void k_final(const float* __restrict__ num, const float* __restrict__ den,
                        const float* __restrict__ Wc, const float* __restrict__ bc,
                        float* __restrict__ out) {
  int t = threadIdx.x;
  int o = t & 15;
  for (int g = t >> 4; g < NG; g += 16) {
    float s = 0.f;
    const float* np = num + (size_t)g * D;
#pragma unroll 8
    for (int c = 0; c < D; c++) s += np[c] * Wc[c * NO + o];
    out[g * NO + o] = s / den[g] + bc[o];
  }
}

// ---------------- launch ----------------
extern "C" void kernel_launch(void* const* d_in, const int* in_sizes, int n_in,
                              void* d_out, int out_size, void* d_ws, size_t ws_size,
                              hipStream_t stream) {
  const float* x   = (const float*)d_in[0];
  const int*   src = (const int*)d_in[1];
  const int*   dst = (const int*)d_in[2];
  const int*   gid = (const int*)d_in[3];
  const float* W1  = (const float*)d_in[4];
  const float* b1  = (const float*)d_in[5];
  const float* W2  = (const float*)d_in[6];
  const float* b2  = (const float*)d_in[7];
  const float* W3  = (const float*)d_in[8];
  const float* b3  = (const float*)d_in[9];
  const float* Wv  = (const float*)d_in[10];
  const float* bv  = (const float*)d_in[11];
  const float* Wc  = (const float*)d_in[12];
  const float* bc  = (const float*)d_in[13];
  float* out = (float*)d_out;

  float* ws = (float*)d_ws;
  float* bufA = ws;                              // 12,800,000 f
  float* bufB = ws + 12800000;                   // 12,800,000 f
  int*   row_ptr = (int*)(ws + 25600000);        // 100,001 i
  int*   fill    = (int*)(ws + 25700004);        // 100,000 i
  int*   eidx    = (int*)(ws + 25800004);        // 1,600,000 i
  float* inv     = ws + 27400004;                // 100,000 f
  float* num     = ws + 27500004;                // 16,384 f
  float* den     = ws + 27516388;                // 128 f   (contiguous after num)

  // ---- CSR build (reused by all 3 layers)
  k_zero<<<98, 256, 0, stream>>>((float*)fill, 25000);
  k_count<<<6250, 256, 0, stream>>>(dst, fill);
  k_scan<<<1, 1024, 0, stream>>>(fill, row_ptr, inv);
  k_zero<<<98, 256, 0, stream>>>((float*)fill, 25000);
  k_fill<<<6250, 256, 0, stream>>>(src, dst, row_ptr, fill, eidx);

  // ---- 3 fused layers (ping-pong; out never aliases gather source)
  k_layer<1><<<1563, 256, 0, stream>>>(x,    row_ptr, eidx, inv, W1, b1, bufA);
  k_layer<1><<<1563, 256, 0, stream>>>(bufA, row_ptr, eidx, inv, W2, b2, bufB);
  k_layer<0><<<1563, 256, 0, stream>>>(bufB, row_ptr, eidx, inv, W3, b3, bufA);

  // ---- readout
  k_zero<<<17, 256, 0, stream>>>(num, 4128);  // num + den contiguous
  k_readout<<<782, 256, 0, stream>>>(bufA, gid, Wv, bv, num, den);
  k_final<<<1, 256, 0, stream>>>(num, den, Wc, bc, out);
}

// Round 3
// 996.338 us; speedup vs baseline: 8.4210x; 1.3957x over previous
//
#include <hip/hip_runtime.h>

#define NN 100000
#define NE 1600000
#define D  128
#define NG 128
#define NO 16

// ---------------- utility ----------------
__global__ void k_zero(float* __restrict__ p, int n4) {
  int i = blockIdx.x * blockDim.x + threadIdx.x;
  float4 z = make_float4(0.f, 0.f, 0.f, 0.f);
  for (; i < n4; i += gridDim.x * blockDim.x) ((float4*)p)[i] = z;
}

// count in-degree into cnt[] (int atomics)
__global__ void k_count(const int* __restrict__ dst, int* __restrict__ cnt) {
  int e = blockIdx.x * blockDim.x + threadIdx.x;
  if (e < NE) atomicAdd(&cnt[dst[e]], 1);
}

// single-block exclusive scan of cnt -> row_ptr, and inv = 1/(deg+1)
__global__ __launch_bounds__(1024) void k_scan(const int* __restrict__ cnt,
                                               int* __restrict__ row_ptr,
                                               float* __restrict__ inv) {
  __shared__ int s[1024];
  const int CH = 98;  // 1024*98 = 100352 >= NN
  int t = threadIdx.x;
  int lo = t * CH;
  int hi = lo + CH; if (hi > NN) hi = NN;
  int sum = 0;
  for (int i = lo; i < hi && i < NN; i++) sum += cnt[i];
  s[t] = sum;
  __syncthreads();
  for (int d = 1; d < 1024; d <<= 1) {
    int x = (t >= d) ? s[t - d] : 0;
    __syncthreads();
    s[t] += x;
    __syncthreads();
  }
  int excl = s[t] - sum;
  int run = excl;
  for (int i = lo; i < hi && i < NN; i++) {
    row_ptr[i] = run;
    int c = cnt[i];
    inv[i] = 1.0f / (float)(c + 1);
    run += c;
  }
  if (t == 1023) row_ptr[NN] = excl;  // empty last chunk -> excl == NE
}

// fill CSR: eidx[row_ptr[d] + k] = src[e]
__global__ void k_fill(const int* __restrict__ src, const int* __restrict__ dst,
                       const int* __restrict__ row_ptr, int* __restrict__ fill,
                       int* __restrict__ eidx) {
  int e = blockIdx.x * blockDim.x + threadIdx.x;
  if (e >= NE) return;
  int d = dst[e];
  int k = atomicAdd(&fill[d], 1);
  eidx[row_ptr[d] + k] = src[e];
}

// ---------------- gather: agg[n] = (sum_{u->n} h[u] + h[n]) / (deg+1) ----------------
// 32 lanes per node, one float4 per lane. Edge loop unrolled x4 with 4
// independent accumulators -> 4 float4 loads in flight per lane. No LDS.
__global__ __launch_bounds__(256) void k_gather(
    const float* __restrict__ h, const int* __restrict__ rp,
    const int* __restrict__ eidx, const float* __restrict__ inv,
    float* __restrict__ agg) {
  int t = blockIdx.x * 256 + threadIdx.x;
  int n = t >> 5;
  int l = t & 31;
  if (n >= NN) return;
  const float4* h4 = (const float4*)h;
  int s0 = rp[n], s1 = rp[n + 1];

  float4 a0 = h4[(size_t)n * 32 + l];  // self
  float4 a1 = make_float4(0.f, 0.f, 0.f, 0.f);
  float4 a2 = make_float4(0.f, 0.f, 0.f, 0.f);
  float4 a3 = make_float4(0.f, 0.f, 0.f, 0.f);

  int i = s0;
  for (; i + 4 <= s1; i += 4) {
    int u0 = eidx[i + 0];
    int u1 = eidx[i + 1];
    int u2 = eidx[i + 2];
    int u3 = eidx[i + 3];
    float4 v0 = h4[(size_t)u0 * 32 + l];
    float4 v1 = h4[(size_t)u1 * 32 + l];
    float4 v2 = h4[(size_t)u2 * 32 + l];
    float4 v3 = h4[(size_t)u3 * 32 + l];
    a0.x += v0.x; a0.y += v0.y; a0.z += v0.z; a0.w += v0.w;
    a1.x += v1.x; a1.y += v1.y; a1.z += v1.z; a1.w += v1.w;
    a2.x += v2.x; a2.y += v2.y; a2.z += v2.z; a2.w += v2.w;
    a3.x += v3.x; a3.y += v3.y; a3.z += v3.z; a3.w += v3.w;
  }
  for (; i < s1; i++) {
    int u = eidx[i];
    float4 v = h4[(size_t)u * 32 + l];
    a0.x += v.x; a0.y += v.y; a0.z += v.z; a0.w += v.w;
  }

  float iv = inv[n];
  float4 r;
  r.x = (a0.x + a1.x + a2.x + a3.x) * iv;
  r.y = (a0.y + a1.y + a2.y + a3.y) * iv;
  r.z = (a0.z + a1.z + a2.z + a3.z) * iv;
  r.w = (a0.w + a1.w + a2.w + a3.w) * iv;
  ((float4*)agg)[(size_t)n * 32 + l] = r;
}

// ---------------- GEMM: out = act(A @ W + b) ----------------
// block 256, 64-node x 128-col tile; A staged coalesced into LDS.
template <int RELU>
__global__ __launch_bounds__(256) void k_gemm(
    const float* __restrict__ A, const float* __restrict__ W,
    const float* __restrict__ b, float* __restrict__ out) {
  __shared__ float sN[64][132];  // +4 pad: row-broadcast reads conflict-free
  __shared__ float sW[32][128];

  int t = threadIdx.x;
  int base = blockIdx.x * 64;

  // stage A tile: 64 rows x 128 cols = 2048 float4, 8 per thread
#pragma unroll
  for (int r = 0; r < 8; r++) {
    int q = t + 256 * r;
    int nl = q >> 5;
    int c4 = (q & 31) * 4;
    int n = base + nl;
    float4 v = make_float4(0.f, 0.f, 0.f, 0.f);
    if (n < NN) v = *(const float4*)(A + (size_t)n * D + c4);
    *(float4*)&sN[nl][c4] = v;
  }

  int tx = t & 15;
  int ty = t >> 4;
  int c0 = tx * 4;
  int c1 = tx * 4 + 64;
  int ty4 = ty * 4;

  float acc[4][8];
#pragma unroll
  for (int i = 0; i < 4; i++)
#pragma unroll
    for (int j = 0; j < 8; j++) acc[i][j] = 0.f;

  for (int kc = 0; kc < D; kc += 32) {
    // stage W chunk: 32 rows x 128 cols = 1024 float4, 4 per thread
#pragma unroll
    for (int r = 0; r < 4; r++) {
      int q = t + 256 * r;
      int kl = q >> 5;
      int c4 = (q & 31) * 4;
      *(float4*)&sW[kl][c4] = *(const float4*)(W + (size_t)(kc + kl) * D + c4);
    }
    __syncthreads();

#pragma unroll 4
    for (int k = 0; k < 32; k++) {
      int kk = kc + k;
      float n0 = sN[ty4 + 0][kk];
      float n1 = sN[ty4 + 1][kk];
      float n2 = sN[ty4 + 2][kk];
      float n3 = sN[ty4 + 3][kk];
      float4 w0 = *(const float4*)&sW[k][c0];
      float4 w1 = *(const float4*)&sW[k][c1];
      acc[0][0] += n0 * w0.x; acc[0][1] += n0 * w0.y; acc[0][2] += n0 * w0.z; acc[0][3] += n0 * w0.w;
      acc[0][4] += n0 * w1.x; acc[0][5] += n0 * w1.y; acc[0][6] += n0 * w1.z; acc[0][7] += n0 * w1.w;
      acc[1][0] += n1 * w0.x; acc[1][1] += n1 * w0.y; acc[1][2] += n1 * w0.z; acc[1][3] += n1 * w0.w;
      acc[1][4] += n1 * w1.x; acc[1][5] += n1 * w1.y; acc[1][6] += n1 * w1.z; acc[1][7] += n1 * w1.w;
      acc[2][0] += n2 * w0.x; acc[2][1] += n2 * w0.y; acc[2][2] += n2 * w0.z; acc[2][3] += n2 * w0.w;
      acc[2][4] += n2 * w1.x; acc[2][5] += n2 * w1.y; acc[2][6] += n2 * w1.z; acc[2][7] += n2 * w1.w;
      acc[3][0] += n3 * w0.x; acc[3][1] += n3 * w0.y; acc[3][2] += n3 * w0.z; acc[3][3] += n3 * w0.w;
      acc[3][4] += n3 * w1.x; acc[3][5] += n3 * w1.y; acc[3][6] += n3 * w1.z; acc[3][7] += n3 * w1.w;
    }
    __syncthreads();
  }

  // epilogue
#pragma unroll
  for (int i = 0; i < 4; i++) {
    int n = base + ty4 + i;
    if (n >= NN) continue;
    float4 o0, o1;
    o0.x = acc[i][0] + b[c0 + 0];
    o0.y = acc[i][1] + b[c0 + 1];
    o0.z = acc[i][2] + b[c0 + 2];
    o0.w = acc[i][3] + b[c0 + 3];
    o1.x = acc[i][4] + b[c1 + 0];
    o1.y = acc[i][5] + b[c1 + 1];
    o1.z = acc[i][6] + b[c1 + 2];
    o1.w = acc[i][7] + b[c1 + 3];
    if (RELU) {
      o0.x = fmaxf(o0.x, 0.f); o0.y = fmaxf(o0.y, 0.f);
      o0.z = fmaxf(o0.z, 0.f); o0.w = fmaxf(o0.w, 0.f);
      o1.x = fmaxf(o1.x, 0.f); o1.y = fmaxf(o1.y, 0.f);
      o1.z = fmaxf(o1.z, 0.f); o1.w = fmaxf(o1.w, 0.f);
    }
    *(float4*)&out[(size_t)n * D + c0] = o0;
    *(float4*)&out[(size_t)n * D + c1] = o1;
  }
}

// ---------------- readout: w = sigmoid(h@Wv+bv); num[g] += w*h; den[g] += w ----------------
__global__ __launch_bounds__(256) void k_readout(
    const float* __restrict__ h, const int* __restrict__ gid,
    const float* __restrict__ Wv, const float* __restrict__ bv,
    float* __restrict__ num, float* __restrict__ den) {
  __shared__ float wl[128];
  int base = blockIdx.x * 128;
  int t = threadIdx.x;

  // phase 1: gate weights (one node per 2 lanes)
  {
    int n = base + (t >> 1);
    int half = t & 1;
    float s = 0.f;
    if (n < NN) {
      const float4* hp = (const float4*)(h + (size_t)n * D + half * 64);
      const float4* wp = (const float4*)(Wv + half * 64);
#pragma unroll
      for (int i = 0; i < 16; i++) {
        float4 a = hp[i], w = wp[i];
        s += a.x * w.x + a.y * w.y + a.z * w.z + a.w * w.w;
      }
    }
    s += __shfl_xor(s, 1);
    if (half == 0) {
      float wv = 0.f;
      if (n < NN) wv = 1.f / (1.f + expf(-(s + bv[0])));
      wl[t >> 1] = wv;
    }
  }
  __syncthreads();

  // phase 2: segmented accumulation (graph_id sorted)
  int c = t & 127;
  int rg = t >> 7;
  float acc = 0.f, wacc = 0.f;
  int cur = -1;
  for (int i = 0; i < 64; i++) {
    int nl = rg * 64 + i;
    int n = base + nl;
    if (n >= NN) break;
    int g = gid[n];
    if (g != cur) {
      if (cur >= 0) {
        unsafeAtomicAdd(&num[(size_t)cur * D + c], acc);
        if (c == 0) unsafeAtomicAdd(&den[cur], wacc);
      }
      cur = g; acc = 0.f; wacc = 0.f;
    }
    float wv = wl[nl];
    acc += wv * h[(size_t)n * D + c];
    if (c == 0) wacc += wv;
  }
  if (cur >= 0) {
    unsafeAtomicAdd(&num[(size_t)cur * D + c], acc);
    if (c == 0) unsafeAtomicAdd(&den[cur], wacc);
  }
}

// ---------------- final: out[g][o] = (num[g]/den[g]) @ Wc + bc ----------------
__global__ void k_final(const float* __restrict__ num, const float* __restrict__ den,
                        const float* __restrict__ Wc, const float* __restrict__ bc,
                        float* __restrict__ out) {
  int t = threadIdx.x;
  int o = t & 15;
  for (int g = t >> 4; g < NG; g += 16) {
    float s = 0.f;
    const float* np = num + (size_t)g * D;
#pragma unroll 8
    for (int c = 0; c < D; c++) s += np[c] * Wc[c * NO + o];
    out[g * NO + o] = s / den[g] + bc[o];
  }
}

// ---------------- launch ----------------
extern "C" void kernel_launch(void* const* d_in, const int* in_sizes, int n_in,
                              void* d_out, int out_size, void* d_ws, size_t ws_size,
                              hipStream_t stream) {
  const float* x   = (const float*)d_in[0];
  const int*   src = (const int*)d_in[1];
  const int*   dst = (const int*)d_in[2];
  const int*   gid = (const int*)d_in[3];
  const float* W1  = (const float*)d_in[4];
  const float* b1  = (const float*)d_in[5];
  const float* W2  = (const float*)d_in[6];
  const float* b2  = (const float*)d_in[7];
  const float* W3  = (const float*)d_in[8];
  const float* b3  = (const float*)d_in[9];
  const float* Wv  = (const float*)d_in[10];
  const float* bv  = (const float*)d_in[11];
  const float* Wc  = (const float*)d_in[12];
  const float* bc  = (const float*)d_in[13];
  float* out = (float*)d_out;

  float* ws = (float*)d_ws;
  float* bufA = ws;                              // 12,800,000 f (agg / ping)
  float* bufB = ws + 12800000;                   // 12,800,000 f (pong)
  int*   row_ptr = (int*)(ws + 25600000);        // 100,001 i
  int*   fill    = (int*)(ws + 25700004);        // 100,000 i
  int*   eidx    = (int*)(ws + 25800004);        // 1,600,000 i
  float* inv     = ws + 27400004;                // 100,000 f
  float* num     = ws + 27500004;                // 16,384 f
  float* den     = ws + 27516388;                // 128 f (contiguous after num)

  // ---- CSR build (reused by all 3 layers)
  k_zero<<<98, 256, 0, stream>>>((float*)fill, 25000);
  k_count<<<6250, 256, 0, stream>>>(dst, fill);
  k_scan<<<1, 1024, 0, stream>>>(fill, row_ptr, inv);
  k_zero<<<98, 256, 0, stream>>>((float*)fill, 25000);
  k_fill<<<6250, 256, 0, stream>>>(src, dst, row_ptr, fill, eidx);

  // ---- 3 layers: gather (random, latency-optimized) then GEMM (streaming)
  // ping-pong: gather src is dead once gather completes, so 2 buffers suffice.
  k_gather<<<12500, 256, 0, stream>>>(x,    row_ptr, eidx, inv, bufA);
  k_gemm<1><<<1563, 256, 0, stream>>>(bufA, W1, b1, bufB);
  k_gather<<<12500, 256, 0, stream>>>(bufB, row_ptr, eidx, inv, bufA);
  k_gemm<1><<<1563, 256, 0, stream>>>(bufA, W2, b2, bufB);
  k_gather<<<12500, 256, 0, stream>>>(bufB, row_ptr, eidx, inv, bufA);
  k_gemm<0><<<1563, 256, 0, stream>>>(bufA, W3, b3, bufB);

  // ---- readout
  k_zero<<<17, 256, 0, stream>>>(num, 4128);  // num + den contiguous
  k_readout<<<782, 256, 0, stream>>>(bufB, gid, Wv, bv, num, den);
  k_final<<<1, 256, 0, stream>>>(num, den, Wc, bc, out);
}

// Round 4
// 663.598 us; speedup vs baseline: 12.6435x; 1.5014x over previous
//
#include <hip/hip_runtime.h>

#define NN 100000
#define NE 1600000
#define D  128
#define NG 128
#define NO 16
#define NB 98  // scan blocks: 98*1024 >= NN

typedef unsigned short u16;

__device__ inline unsigned short f2bf(float f) {  // RNE float->bf16
  unsigned u = __float_as_uint(f);
  unsigned r = u + 0x7fffu + ((u >> 16) & 1u);
  return (unsigned short)(r >> 16);
}
__device__ inline unsigned pk2(float a, float b) {
  return (unsigned)f2bf(a) | ((unsigned)f2bf(b) << 16);
}

// ---------------- utility ----------------
__global__ void k_zero(float* __restrict__ p, int n4) {
  int i = blockIdx.x * blockDim.x + threadIdx.x;
  float4 z = make_float4(0.f, 0.f, 0.f, 0.f);
  for (; i < n4; i += gridDim.x * blockDim.x) ((float4*)p)[i] = z;
}

__global__ void k_count(const int* __restrict__ dst, int* __restrict__ cnt) {
  int e = blockIdx.x * blockDim.x + threadIdx.x;
  if (e < NE) atomicAdd(&cnt[dst[e]], 1);
}

// ---------------- 3-stage scan (coalesced) ----------------
// stage 1: per-block (1024 elems) sums
__global__ __launch_bounds__(256) void k_scan1(const int* __restrict__ cnt,
                                               int* __restrict__ bsum) {
  int b = blockIdx.x, t = threadIdx.x;
  int i0 = b * 1024 + t * 4;
  int4 v = make_int4(0, 0, 0, 0);
  if (i0 < NN) v = *(const int4*)(cnt + i0);  // NN%4==0: no straddle
  int s = v.x + v.y + v.z + v.w;
#pragma unroll
  for (int d = 1; d < 64; d <<= 1) s += __shfl_xor(s, d);
  __shared__ int ws[4];
  if ((t & 63) == 0) ws[t >> 6] = s;
  __syncthreads();
  if (t == 0) bsum[b] = ws[0] + ws[1] + ws[2] + ws[3];
}

// stage 2: exclusive scan of NB block sums; also writes row_ptr[NN] = NE
__global__ __launch_bounds__(128) void k_scan2(int* __restrict__ bsum,
                                               int* __restrict__ row_ptr) {
  __shared__ int s[128];
  int t = threadIdx.x;
  int v = (t < NB) ? bsum[t] : 0;
  s[t] = v;
  __syncthreads();
#pragma unroll
  for (int d = 1; d < 128; d <<= 1) {
    int x = (t >= d) ? s[t - d] : 0;
    __syncthreads();
    s[t] += x;
    __syncthreads();
  }
  if (t < NB) bsum[t] = s[t] - v;       // exclusive
  if (t == 127) row_ptr[NN] = s[127];   // total == NE
}

// stage 3: write row_ptr (exclusive prefix) and inv = 1/(deg+1)
__global__ __launch_bounds__(256) void k_scan3(const int* __restrict__ cnt,
                                               const int* __restrict__ bsum,
                                               int* __restrict__ row_ptr,
                                               float* __restrict__ inv) {
  int b = blockIdx.x, t = threadIdx.x;
  int i0 = b * 1024 + t * 4;
  int4 v = make_int4(0, 0, 0, 0);
  if (i0 < NN) v = *(const int4*)(cnt + i0);
  int tsum = v.x + v.y + v.z + v.w;
  int lane = t & 63;
  int incl = tsum;
#pragma unroll
  for (int d = 1; d < 64; d <<= 1) {
    int x = __shfl_up(incl, d);
    if (lane >= d) incl += x;
  }
  __shared__ int wsum[4];
  if (lane == 63) wsum[t >> 6] = incl;
  __syncthreads();
  int base = bsum[b] + incl - tsum;
  int w = t >> 6;
#pragma unroll
  for (int i = 0; i < 4; i++) base += (i < w) ? wsum[i] : 0;
  if (i0 < NN) {
    int e0 = base, e1 = e0 + v.x, e2 = e1 + v.y, e3 = e2 + v.z;
    *(int4*)(row_ptr + i0) = make_int4(e0, e1, e2, e3);
    float4 iv;
    iv.x = 1.f / (float)(v.x + 1);
    iv.y = 1.f / (float)(v.y + 1);
    iv.z = 1.f / (float)(v.z + 1);
    iv.w = 1.f / (float)(v.w + 1);
    *(float4*)(inv + i0) = iv;
  }
}

// fill CSR: eidx[row_ptr[d] + k] = src[e]
__global__ void k_fill(const int* __restrict__ src, const int* __restrict__ dst,
                       const int* __restrict__ row_ptr, int* __restrict__ fill,
                       int* __restrict__ eidx) {
  int e = blockIdx.x * blockDim.x + threadIdx.x;
  if (e >= NE) return;
  int d = dst[e];
  int k = atomicAdd(&fill[d], 1);
  eidx[row_ptr[d] + k] = src[e];
}

// ---------------- convert f32 -> bf16 shadow ----------------
__global__ void k_conv(const float* __restrict__ x, uint2* __restrict__ xb) {
  int i = blockIdx.x * 256 + threadIdx.x;  // one float4 -> one uint2 (4 bf16)
  if (i < NN * 32) {
    float4 v = ((const float4*)x)[i];
    xb[i] = make_uint2(pk2(v.x, v.y), pk2(v.z, v.w));
  }
}

// ---------------- gather: out[n] = (sum_{u->n} hb[u] + hs[n]) * inv[n] ----------------
// neighbors from bf16 shadow hb, self from fp32 hs. out may alias hs
// (each thread reads only its own row of hs, writes the same address after).
__global__ __launch_bounds__(256) void k_gather(
    const uint2* __restrict__ hb, const float* __restrict__ hs,
    const int* __restrict__ rp, const int* __restrict__ eidx,
    const float* __restrict__ inv, float* __restrict__ out) {
  int t = blockIdx.x * 256 + threadIdx.x;
  int n = t >> 5;
  int l = t & 31;  // 4-column group
  if (n >= NN) return;
  int s0 = rp[n], s1 = rp[n + 1];

  float4 a0 = ((const float4*)hs)[(size_t)n * 32 + l];  // self (fp32)
  float4 a1 = make_float4(0.f, 0.f, 0.f, 0.f);
  float4 a2 = make_float4(0.f, 0.f, 0.f, 0.f);
  float4 a3 = make_float4(0.f, 0.f, 0.f, 0.f);

  int i = s0;
  for (; i + 4 <= s1; i += 4) {
    int u0 = eidx[i + 0];
    int u1 = eidx[i + 1];
    int u2 = eidx[i + 2];
    int u3 = eidx[i + 3];
    uint2 q0 = hb[(size_t)u0 * 32 + l];
    uint2 q1 = hb[(size_t)u1 * 32 + l];
    uint2 q2 = hb[(size_t)u2 * 32 + l];
    uint2 q3 = hb[(size_t)u3 * 32 + l];
    a0.x += __uint_as_float(q0.x << 16);
    a0.y += __uint_as_float(q0.x & 0xffff0000u);
    a0.z += __uint_as_float(q0.y << 16);
    a0.w += __uint_as_float(q0.y & 0xffff0000u);
    a1.x += __uint_as_float(q1.x << 16);
    a1.y += __uint_as_float(q1.x & 0xffff0000u);
    a1.z += __uint_as_float(q1.y << 16);
    a1.w += __uint_as_float(q1.y & 0xffff0000u);
    a2.x += __uint_as_float(q2.x << 16);
    a2.y += __uint_as_float(q2.x & 0xffff0000u);
    a2.z += __uint_as_float(q2.y << 16);
    a2.w += __uint_as_float(q2.y & 0xffff0000u);
    a3.x += __uint_as_float(q3.x << 16);
    a3.y += __uint_as_float(q3.x & 0xffff0000u);
    a3.z += __uint_as_float(q3.y << 16);
    a3.w += __uint_as_float(q3.y & 0xffff0000u);
  }
  for (; i < s1; i++) {
    int u = eidx[i];
    uint2 q = hb[(size_t)u * 32 + l];
    a0.x += __uint_as_float(q.x << 16);
    a0.y += __uint_as_float(q.x & 0xffff0000u);
    a0.z += __uint_as_float(q.y << 16);
    a0.w += __uint_as_float(q.y & 0xffff0000u);
  }

  float iv = inv[n];
  float4 r;
  r.x = (a0.x + a1.x + a2.x + a3.x) * iv;
  r.y = (a0.y + a1.y + a2.y + a3.y) * iv;
  r.z = (a0.z + a1.z + a2.z + a3.z) * iv;
  r.w = (a0.w + a1.w + a2.w + a3.w) * iv;
  ((float4*)out)[(size_t)n * 32 + l] = r;
}

// ---------------- GEMM: out = act(A @ W + b); optional bf16 sidecar ----------------
// In-place safe (out==A): each block stages its own 64 rows first, writes last.
template <int RELU, int WB>
__global__ __launch_bounds__(256) void k_gemm(
    const float* __restrict__ A, const float* __restrict__ W,
    const float* __restrict__ b, float* __restrict__ out,
    uint2* __restrict__ outb) {
  __shared__ float sN[64][132];  // +4 pad: row-broadcast reads conflict-free
  __shared__ float sW[32][128];

  int t = threadIdx.x;
  int base = blockIdx.x * 64;

  // stage A tile: 64 rows x 128 cols = 2048 float4, 8 per thread
#pragma unroll
  for (int r = 0; r < 8; r++) {
    int q = t + 256 * r;
    int nl = q >> 5;
    int c4 = (q & 31) * 4;
    int n = base + nl;
    float4 v = make_float4(0.f, 0.f, 0.f, 0.f);
    if (n < NN) v = *(const float4*)(A + (size_t)n * D + c4);
    *(float4*)&sN[nl][c4] = v;
  }

  int tx = t & 15;
  int ty = t >> 4;
  int c0 = tx * 4;
  int c1 = tx * 4 + 64;
  int ty4 = ty * 4;

  float acc[4][8];
#pragma unroll
  for (int i = 0; i < 4; i++)
#pragma unroll
    for (int j = 0; j < 8; j++) acc[i][j] = 0.f;

  for (int kc = 0; kc < D; kc += 32) {
#pragma unroll
    for (int r = 0; r < 4; r++) {
      int q = t + 256 * r;
      int kl = q >> 5;
      int c4 = (q & 31) * 4;
      *(float4*)&sW[kl][c4] = *(const float4*)(W + (size_t)(kc + kl) * D + c4);
    }
    __syncthreads();

#pragma unroll 4
    for (int k = 0; k < 32; k++) {
      int kk = kc + k;
      float n0 = sN[ty4 + 0][kk];
      float n1 = sN[ty4 + 1][kk];
      float n2 = sN[ty4 + 2][kk];
      float n3 = sN[ty4 + 3][kk];
      float4 w0 = *(const float4*)&sW[k][c0];
      float4 w1 = *(const float4*)&sW[k][c1];
      acc[0][0] += n0 * w0.x; acc[0][1] += n0 * w0.y; acc[0][2] += n0 * w0.z; acc[0][3] += n0 * w0.w;
      acc[0][4] += n0 * w1.x; acc[0][5] += n0 * w1.y; acc[0][6] += n0 * w1.z; acc[0][7] += n0 * w1.w;
      acc[1][0] += n1 * w0.x; acc[1][1] += n1 * w0.y; acc[1][2] += n1 * w0.z; acc[1][3] += n1 * w0.w;
      acc[1][4] += n1 * w1.x; acc[1][5] += n1 * w1.y; acc[1][6] += n1 * w1.z; acc[1][7] += n1 * w1.w;
      acc[2][0] += n2 * w0.x; acc[2][1] += n2 * w0.y; acc[2][2] += n2 * w0.z; acc[2][3] += n2 * w0.w;
      acc[2][4] += n2 * w1.x; acc[2][5] += n2 * w1.y; acc[2][6] += n2 * w1.z; acc[2][7] += n2 * w1.w;
      acc[3][0] += n3 * w0.x; acc[3][1] += n3 * w0.y; acc[3][2] += n3 * w0.z; acc[3][3] += n3 * w0.w;
      acc[3][4] += n3 * w1.x; acc[3][5] += n3 * w1.y; acc[3][6] += n3 * w1.z; acc[3][7] += n3 * w1.w;
    }
    __syncthreads();
  }

#pragma unroll
  for (int i = 0; i < 4; i++) {
    int n = base + ty4 + i;
    if (n >= NN) continue;
    float4 o0, o1;
    o0.x = acc[i][0] + b[c0 + 0];
    o0.y = acc[i][1] + b[c0 + 1];
    o0.z = acc[i][2] + b[c0 + 2];
    o0.w = acc[i][3] + b[c0 + 3];
    o1.x = acc[i][4] + b[c1 + 0];
    o1.y = acc[i][5] + b[c1 + 1];
    o1.z = acc[i][6] + b[c1 + 2];
    o1.w = acc[i][7] + b[c1 + 3];
    if (RELU) {
      o0.x = fmaxf(o0.x, 0.f); o0.y = fmaxf(o0.y, 0.f);
      o0.z = fmaxf(o0.z, 0.f); o0.w = fmaxf(o0.w, 0.f);
      o1.x = fmaxf(o1.x, 0.f); o1.y = fmaxf(o1.y, 0.f);
      o1.z = fmaxf(o1.z, 0.f); o1.w = fmaxf(o1.w, 0.f);
    }
    *(float4*)&out[(size_t)n * D + c0] = o0;
    *(float4*)&out[(size_t)n * D + c1] = o1;
    if (WB) {
      outb[(size_t)n * 32 + tx]      = make_uint2(pk2(o0.x, o0.y), pk2(o0.z, o0.w));
      outb[(size_t)n * 32 + 16 + tx] = make_uint2(pk2(o1.x, o1.y), pk2(o1.z, o1.w));
    }
  }
}

// ---------------- readout ----------------
__global__ __launch_bounds__(256) void k_readout(
    const float* __restrict__ h, const int* __restrict__ gid,
    const float* __restrict__ Wv, const float* __restrict__ bv,
    float* __restrict__ num, float* __restrict__ den) {
  __shared__ float wl[128];
  int base = blockIdx.x * 128;
  int t = threadIdx.x;

  {
    int n = base + (t >> 1);
    int half = t & 1;
    float s = 0.f;
    if (n < NN) {
      const float4* hp = (const float4*)(h + (size_t)n * D + half * 64);
      const float4* wp = (const float4*)(Wv + half * 64);
#pragma unroll
      for (int i = 0; i < 16; i++) {
        float4 a = hp[i], w = wp[i];
        s += a.x * w.x + a.y * w.y + a.z * w.z + a.w * w.w;
      }
    }
    s += __shfl_xor(s, 1);
    if (half == 0) {
      float wv = 0.f;
      if (n < NN) wv = 1.f / (1.f + expf(-(s + bv[0])));
      wl[t >> 1] = wv;
    }
  }
  __syncthreads();

  int c = t & 127;
  int rg = t >> 7;
  float acc = 0.f, wacc = 0.f;
  int cur = -1;
  for (int i = 0; i < 64; i++) {
    int nl = rg * 64 + i;
    int n = base + nl;
    if (n >= NN) break;
    int g = gid[n];
    if (g != cur) {
      if (cur >= 0) {
        unsafeAtomicAdd(&num[(size_t)cur * D + c], acc);
        if (c == 0) unsafeAtomicAdd(&den[cur], wacc);
      }
      cur = g; acc = 0.f; wacc = 0.f;
    }
    float wv = wl[nl];
    acc += wv * h[(size_t)n * D + c];
    if (c == 0) wacc += wv;
  }
  if (cur >= 0) {
    unsafeAtomicAdd(&num[(size_t)cur * D + c], acc);
    if (c == 0) unsafeAtomicAdd(&den[cur], wacc);
  }
}

// ---------------- final ----------------
__global__ void k_final(const float* __restrict__ num, const float* __restrict__ den,
                        const float* __restrict__ Wc, const float* __restrict__ bc,
                        float* __restrict__ out) {
  int t = threadIdx.x;
  int o = t & 15;
  for (int g = t >> 4; g < NG; g += 16) {
    float s = 0.f;
    const float* np = num + (size_t)g * D;
#pragma unroll 8
    for (int c = 0; c < D; c++) s += np[c] * Wc[c * NO + o];
    out[g * NO + o] = s / den[g] + bc[o];
  }
}

// ---------------- launch ----------------
extern "C" void kernel_launch(void* const* d_in, const int* in_sizes, int n_in,
                              void* d_out, int out_size, void* d_ws, size_t ws_size,
                              hipStream_t stream) {
  const float* x   = (const float*)d_in[0];
  const int*   src = (const int*)d_in[1];
  const int*   dst = (const int*)d_in[2];
  const int*   gid = (const int*)d_in[3];
  const float* W1  = (const float*)d_in[4];
  const float* b1  = (const float*)d_in[5];
  const float* W2  = (const float*)d_in[6];
  const float* b2  = (const float*)d_in[7];
  const float* W3  = (const float*)d_in[8];
  const float* b3  = (const float*)d_in[9];
  const float* Wv  = (const float*)d_in[10];
  const float* bv  = (const float*)d_in[11];
  const float* Wc  = (const float*)d_in[12];
  const float* bc  = (const float*)d_in[13];
  float* out = (float*)d_out;

  float* ws = (float*)d_ws;
  float* C       = ws;                       // 12,800,000 f : h / agg (in-place chain)
  uint2* hb      = (uint2*)(ws + 12800000);  // 6,400,000 f  : bf16 shadow [NN][128]
  int*   row_ptr = (int*)(ws + 19200000);    // 100,001 i
  int*   fill    = (int*)(ws + 19300004);    // 100,000 i
  int*   eidx    = (int*)(ws + 19400004);    // 1,600,000 i
  float* inv     = ws + 21000004;            // 100,000 f
  float* num     = ws + 21100004;            // 16,384 f
  float* den     = ws + 21116388;            // 128 f (contiguous after num)
  int*   bsum    = (int*)(ws + 21116516);    // 128 i

  // ---- CSR build
  k_zero<<<98, 256, 0, stream>>>((float*)fill, 25000);
  k_count<<<6250, 256, 0, stream>>>(dst, fill);
  k_scan1<<<NB, 256, 0, stream>>>(fill, bsum);
  k_scan2<<<1, 128, 0, stream>>>(bsum, row_ptr);
  k_scan3<<<NB, 256, 0, stream>>>(fill, bsum, row_ptr, inv);
  k_zero<<<98, 256, 0, stream>>>((float*)fill, 25000);
  k_fill<<<6250, 256, 0, stream>>>(src, dst, row_ptr, fill, eidx);

  // ---- bf16 shadow of x
  k_conv<<<12500, 256, 0, stream>>>(x, hb);

  // ---- 3 layers (gather in-place-safe; gemm in-place, writes next bf16 shadow)
  k_gather<<<12500, 256, 0, stream>>>(hb, x, row_ptr, eidx, inv, C);
  k_gemm<1, 1><<<1563, 256, 0, stream>>>(C, W1, b1, C, hb);
  k_gather<<<12500, 256, 0, stream>>>(hb, C, row_ptr, eidx, inv, C);
  k_gemm<1, 1><<<1563, 256, 0, stream>>>(C, W2, b2, C, hb);
  k_gather<<<12500, 256, 0, stream>>>(hb, C, row_ptr, eidx, inv, C);
  k_gemm<0, 0><<<1563, 256, 0, stream>>>(C, W3, b3, C, nullptr);

  // ---- readout
  k_zero<<<17, 256, 0, stream>>>(num, 4128);  // num + den contiguous
  k_readout<<<782, 256, 0, stream>>>(C, gid, Wv, bv, num, den);
  k_final<<<1, 256, 0, stream>>>(num, den, Wc, bc, out);
}

// Round 5
// 528.371 us; speedup vs baseline: 15.8793x; 1.2559x over previous
//
#include <hip/hip_runtime.h>

#define NN 100000
#define NE 1600000
#define D  128
#define NG 128
#define NO 16
#define NB 98     // scan blocks: 98*1024 >= NN
#define NBUK 391  // dst>>8 buckets: 391*256 >= NN
#define G3 256    // blocks for hist/scatter; G3 * 6250 == NE

__device__ inline unsigned short f2bf(float f) {  // RNE float->bf16
  unsigned u = __float_as_uint(f);
  unsigned r = u + 0x7fffu + ((u >> 16) & 1u);
  return (unsigned short)(r >> 16);
}
__device__ inline unsigned pk2(float a, float b) {
  return (unsigned)f2bf(a) | ((unsigned)f2bf(b) << 16);
}

// ---------------- utility ----------------
__global__ void k_zero(float* __restrict__ p, int n4) {
  int i = blockIdx.x * blockDim.x + threadIdx.x;
  float4 z = make_float4(0.f, 0.f, 0.f, 0.f);
  for (; i < n4; i += gridDim.x * blockDim.x) ((float4*)p)[i] = z;
}

// ---------------- bucketed CSR build ----------------
// stage A: bucket histogram (LDS per block, merge to global)
__global__ __launch_bounds__(256) void f_hist(const int* __restrict__ dst,
                                              int* __restrict__ bsumG) {
  __shared__ int h[NBUK];
  for (int i = threadIdx.x; i < NBUK; i += 256) h[i] = 0;
  __syncthreads();
  int lo = blockIdx.x * (NE / G3), hi = lo + (NE / G3);
  for (int e = lo + threadIdx.x; e < hi; e += 256) atomicAdd(&h[dst[e] >> 8], 1);
  __syncthreads();
  for (int i = threadIdx.x; i < NBUK; i += 256)
    if (h[i]) atomicAdd(&bsumG[i], h[i]);
}

// stage B: exclusive scan of bucket sums -> bbase; bfill = copy
__global__ __launch_bounds__(512) void f_bscan(const int* __restrict__ bsumG,
                                               int* __restrict__ bbase,
                                               int* __restrict__ bfill) {
  __shared__ int s[512];
  int t = threadIdx.x;
  int v = (t < NBUK) ? bsumG[t] : 0;
  s[t] = v;
  __syncthreads();
  for (int d = 1; d < 512; d <<= 1) {
    int x = (t >= d) ? s[t - d] : 0;
    __syncthreads();
    s[t] += x;
    __syncthreads();
  }
  if (t < NBUK) {
    int e = s[t] - v;
    bbase[t] = e;
    bfill[t] = e;
  }
  if (t == NBUK - 1) bbase[NBUK] = s[t];  // == NE
}

// stage C: scatter (src,dst) pairs bucket-grouped; per-(block,bucket) runs
__global__ __launch_bounds__(256) void f_scatter(const int* __restrict__ src,
                                                 const int* __restrict__ dst,
                                                 int* __restrict__ bfill,
                                                 uint2* __restrict__ ebuf) {
  __shared__ int h[NBUK];
  __shared__ int base[NBUK];
  for (int i = threadIdx.x; i < NBUK; i += 256) h[i] = 0;
  __syncthreads();
  int lo = blockIdx.x * (NE / G3), hi = lo + (NE / G3);
  for (int e = lo + threadIdx.x; e < hi; e += 256) atomicAdd(&h[dst[e] >> 8], 1);
  __syncthreads();
  for (int i = threadIdx.x; i < NBUK; i += 256) {
    int c = h[i];
    base[i] = c ? atomicAdd(&bfill[i], c) : 0;
  }
  __syncthreads();
  for (int i = threadIdx.x; i < NBUK; i += 256) h[i] = 0;
  __syncthreads();
  for (int e = lo + threadIdx.x; e < hi; e += 256) {
    int d = dst[e];
    int b = d >> 8;
    int k = atomicAdd(&h[b], 1);
    ebuf[base[b] + k] = make_uint2((unsigned)src[e], (unsigned)d);
  }
}

// stage D: per-bucket node counts (LDS counters, coalesced non-atomic write)
__global__ __launch_bounds__(256) void f_count(const uint2* __restrict__ ebuf,
                                               const int* __restrict__ bbase,
                                               int* __restrict__ cnt) {
  __shared__ int c[256];
  int b = blockIdx.x;
  c[threadIdx.x] = 0;
  __syncthreads();
  int lo = bbase[b], hi = bbase[b + 1];
  for (int i = lo + threadIdx.x; i < hi; i += 256)
    atomicAdd(&c[ebuf[i].y & 255], 1);
  __syncthreads();
  int n = (b << 8) + threadIdx.x;
  if (n < NN) cnt[n] = c[threadIdx.x];
}

// stage F: per-bucket CSR fill (LDS counters; eidx writes local to ~16KB span)
__global__ __launch_bounds__(256) void f_fill(const uint2* __restrict__ ebuf,
                                              const int* __restrict__ bbase,
                                              const int* __restrict__ row_ptr,
                                              int* __restrict__ eidx) {
  __shared__ int fl[256];
  __shared__ int rp[256];
  int b = blockIdx.x;
  int n = (b << 8) + threadIdx.x;
  fl[threadIdx.x] = 0;
  rp[threadIdx.x] = (n < NN) ? row_ptr[n] : 0;
  __syncthreads();
  int lo = bbase[b], hi = bbase[b + 1];
  for (int i = lo + threadIdx.x; i < hi; i += 256) {
    uint2 p = ebuf[i];
    int dl = p.y & 255;
    int k = atomicAdd(&fl[dl], 1);
    eidx[rp[dl] + k] = (int)p.x;
  }
}

// ---------------- 3-stage scan over cnt -> row_ptr, inv ----------------
__global__ __launch_bounds__(256) void k_scan1(const int* __restrict__ cnt,
                                               int* __restrict__ bsum) {
  int b = blockIdx.x, t = threadIdx.x;
  int i0 = b * 1024 + t * 4;
  int4 v = make_int4(0, 0, 0, 0);
  if (i0 < NN) v = *(const int4*)(cnt + i0);
  int s = v.x + v.y + v.z + v.w;
#pragma unroll
  for (int d = 1; d < 64; d <<= 1) s += __shfl_xor(s, d);
  __shared__ int ws[4];
  if ((t & 63) == 0) ws[t >> 6] = s;
  __syncthreads();
  if (t == 0) bsum[b] = ws[0] + ws[1] + ws[2] + ws[3];
}

__global__ __launch_bounds__(128) void k_scan2(int* __restrict__ bsum,
                                               int* __restrict__ row_ptr) {
  __shared__ int s[128];
  int t = threadIdx.x;
  int v = (t < NB) ? bsum[t] : 0;
  s[t] = v;
  __syncthreads();
#pragma unroll
  for (int d = 1; d < 128; d <<= 1) {
    int x = (t >= d) ? s[t - d] : 0;
    __syncthreads();
    s[t] += x;
    __syncthreads();
  }
  if (t < NB) bsum[t] = s[t] - v;
  if (t == 127) row_ptr[NN] = s[127];
}

__global__ __launch_bounds__(256) void k_scan3(const int* __restrict__ cnt,
                                               const int* __restrict__ bsum,
                                               int* __restrict__ row_ptr,
                                               float* __restrict__ inv) {
  int b = blockIdx.x, t = threadIdx.x;
  int i0 = b * 1024 + t * 4;
  int4 v = make_int4(0, 0, 0, 0);
  if (i0 < NN) v = *(const int4*)(cnt + i0);
  int tsum = v.x + v.y + v.z + v.w;
  int lane = t & 63;
  int incl = tsum;
#pragma unroll
  for (int d = 1; d < 64; d <<= 1) {
    int x = __shfl_up(incl, d);
    if (lane >= d) incl += x;
  }
  __shared__ int wsum[4];
  if (lane == 63) wsum[t >> 6] = incl;
  __syncthreads();
  int base = bsum[b] + incl - tsum;
  int w = t >> 6;
#pragma unroll
  for (int i = 0; i < 4; i++) base += (i < w) ? wsum[i] : 0;
  if (i0 < NN) {
    int e0 = base, e1 = e0 + v.x, e2 = e1 + v.y, e3 = e2 + v.z;
    *(int4*)(row_ptr + i0) = make_int4(e0, e1, e2, e3);
    float4 iv;
    iv.x = 1.f / (float)(v.x + 1);
    iv.y = 1.f / (float)(v.y + 1);
    iv.z = 1.f / (float)(v.z + 1);
    iv.w = 1.f / (float)(v.w + 1);
    *(float4*)(inv + i0) = iv;
  }
}

// ---------------- convert f32 -> bf16 shadow ----------------
__global__ void k_conv(const float* __restrict__ x, uint2* __restrict__ xb) {
  int i = blockIdx.x * 256 + threadIdx.x;
  if (i < NN * 32) {
    float4 v = ((const float4*)x)[i];
    xb[i] = make_uint2(pk2(v.x, v.y), pk2(v.z, v.w));
  }
}

// ---------------- gather: out[n] = (sum_{u->n} hb[u] + hs[n]) * inv[n] ----------------
// 32 lanes per node; 8 row loads in flight per lane. out may alias hs.
__global__ __launch_bounds__(256) void k_gather(
    const uint2* __restrict__ hb, const float* __restrict__ hs,
    const int* __restrict__ rp, const int* __restrict__ eidx,
    const float* __restrict__ inv, float* __restrict__ out) {
  int t = blockIdx.x * 256 + threadIdx.x;
  int n = t >> 5;
  int l = t & 31;
  if (n >= NN) return;
  int s0 = rp[n], s1 = rp[n + 1];

  float4 a0 = ((const float4*)hs)[(size_t)n * 32 + l];  // self (fp32)
  float4 a1 = make_float4(0.f, 0.f, 0.f, 0.f);
  float4 a2 = make_float4(0.f, 0.f, 0.f, 0.f);
  float4 a3 = make_float4(0.f, 0.f, 0.f, 0.f);

  int i = s0;
  for (; i + 8 <= s1; i += 8) {
    int u[8];
    uint2 q[8];
#pragma unroll
    for (int j = 0; j < 8; j++) u[j] = eidx[i + j];
#pragma unroll
    for (int j = 0; j < 8; j++) q[j] = hb[(size_t)u[j] * 32 + l];
#pragma unroll
    for (int j = 0; j < 8; j++) {
      float4* a = (j & 2) ? ((j & 1) ? &a3 : &a2) : ((j & 1) ? &a1 : &a0);
      a->x += __uint_as_float(q[j].x << 16);
      a->y += __uint_as_float(q[j].x & 0xffff0000u);
      a->z += __uint_as_float(q[j].y << 16);
      a->w += __uint_as_float(q[j].y & 0xffff0000u);
    }
  }
  for (; i + 4 <= s1; i += 4) {
    int u[4];
    uint2 q[4];
#pragma unroll
    for (int j = 0; j < 4; j++) u[j] = eidx[i + j];
#pragma unroll
    for (int j = 0; j < 4; j++) q[j] = hb[(size_t)u[j] * 32 + l];
#pragma unroll
    for (int j = 0; j < 4; j++) {
      float4* a = (j & 2) ? ((j & 1) ? &a3 : &a2) : ((j & 1) ? &a1 : &a0);
      a->x += __uint_as_float(q[j].x << 16);
      a->y += __uint_as_float(q[j].x & 0xffff0000u);
      a->z += __uint_as_float(q[j].y << 16);
      a->w += __uint_as_float(q[j].y & 0xffff0000u);
    }
  }
  for (; i < s1; i++) {
    uint2 q = hb[(size_t)eidx[i] * 32 + l];
    a0.x += __uint_as_float(q.x << 16);
    a0.y += __uint_as_float(q.x & 0xffff0000u);
    a0.z += __uint_as_float(q.y << 16);
    a0.w += __uint_as_float(q.y & 0xffff0000u);
  }

  float iv = inv[n];
  float4 r;
  r.x = (a0.x + a1.x + a2.x + a3.x) * iv;
  r.y = (a0.y + a1.y + a2.y + a3.y) * iv;
  r.z = (a0.z + a1.z + a2.z + a3.z) * iv;
  r.w = (a0.w + a1.w + a2.w + a3.w) * iv;
  ((float4*)out)[(size_t)n * 32 + l] = r;
}

// ---------------- GEMM: out = act(A @ W + b); optional bf16 sidecar ----------------
template <int RELU, int WB>
__global__ __launch_bounds__(256) void k_gemm(
    const float* __restrict__ A, const float* __restrict__ W,
    const float* __restrict__ b, float* __restrict__ out,
    uint2* __restrict__ outb) {
  __shared__ float sN[64][132];
  __shared__ float sW[32][128];

  int t = threadIdx.x;
  int base = blockIdx.x * 64;

#pragma unroll
  for (int r = 0; r < 8; r++) {
    int q = t + 256 * r;
    int nl = q >> 5;
    int c4 = (q & 31) * 4;
    int n = base + nl;
    float4 v = make_float4(0.f, 0.f, 0.f, 0.f);
    if (n < NN) v = *(const float4*)(A + (size_t)n * D + c4);
    *(float4*)&sN[nl][c4] = v;
  }

  int tx = t & 15;
  int ty = t >> 4;
  int c0 = tx * 4;
  int c1 = tx * 4 + 64;
  int ty4 = ty * 4;

  float acc[4][8];
#pragma unroll
  for (int i = 0; i < 4; i++)
#pragma unroll
    for (int j = 0; j < 8; j++) acc[i][j] = 0.f;

  for (int kc = 0; kc < D; kc += 32) {
#pragma unroll
    for (int r = 0; r < 4; r++) {
      int q = t + 256 * r;
      int kl = q >> 5;
      int c4 = (q & 31) * 4;
      *(float4*)&sW[kl][c4] = *(const float4*)(W + (size_t)(kc + kl) * D + c4);
    }
    __syncthreads();

#pragma unroll 4
    for (int k = 0; k < 32; k++) {
      int kk = kc + k;
      float n0 = sN[ty4 + 0][kk];
      float n1 = sN[ty4 + 1][kk];
      float n2 = sN[ty4 + 2][kk];
      float n3 = sN[ty4 + 3][kk];
      float4 w0 = *(const float4*)&sW[k][c0];
      float4 w1 = *(const float4*)&sW[k][c1];
      acc[0][0] += n0 * w0.x; acc[0][1] += n0 * w0.y; acc[0][2] += n0 * w0.z; acc[0][3] += n0 * w0.w;
      acc[0][4] += n0 * w1.x; acc[0][5] += n0 * w1.y; acc[0][6] += n0 * w1.z; acc[0][7] += n0 * w1.w;
      acc[1][0] += n1 * w0.x; acc[1][1] += n1 * w0.y; acc[1][2] += n1 * w0.z; acc[1][3] += n1 * w0.w;
      acc[1][4] += n1 * w1.x; acc[1][5] += n1 * w1.y; acc[1][6] += n1 * w1.z; acc[1][7] += n1 * w1.w;
      acc[2][0] += n2 * w0.x; acc[2][1] += n2 * w0.y; acc[2][2] += n2 * w0.z; acc[2][3] += n2 * w0.w;
      acc[2][4] += n2 * w1.x; acc[2][5] += n2 * w1.y; acc[2][6] += n2 * w1.z; acc[2][7] += n2 * w1.w;
      acc[3][0] += n3 * w0.x; acc[3][1] += n3 * w0.y; acc[3][2] += n3 * w0.z; acc[3][3] += n3 * w0.w;
      acc[3][4] += n3 * w1.x; acc[3][5] += n3 * w1.y; acc[3][6] += n3 * w1.z; acc[3][7] += n3 * w1.w;
    }
    __syncthreads();
  }

#pragma unroll
  for (int i = 0; i < 4; i++) {
    int n = base + ty4 + i;
    if (n >= NN) continue;
    float4 o0, o1;
    o0.x = acc[i][0] + b[c0 + 0];
    o0.y = acc[i][1] + b[c0 + 1];
    o0.z = acc[i][2] + b[c0 + 2];
    o0.w = acc[i][3] + b[c0 + 3];
    o1.x = acc[i][4] + b[c1 + 0];
    o1.y = acc[i][5] + b[c1 + 1];
    o1.z = acc[i][6] + b[c1 + 2];
    o1.w = acc[i][7] + b[c1 + 3];
    if (RELU) {
      o0.x = fmaxf(o0.x, 0.f); o0.y = fmaxf(o0.y, 0.f);
      o0.z = fmaxf(o0.z, 0.f); o0.w = fmaxf(o0.w, 0.f);
      o1.x = fmaxf(o1.x, 0.f); o1.y = fmaxf(o1.y, 0.f);
      o1.z = fmaxf(o1.z, 0.f); o1.w = fmaxf(o1.w, 0.f);
    }
    *(float4*)&out[(size_t)n * D + c0] = o0;
    *(float4*)&out[(size_t)n * D + c1] = o1;
    if (WB) {
      outb[(size_t)n * 32 + tx]      = make_uint2(pk2(o0.x, o0.y), pk2(o0.z, o0.w));
      outb[(size_t)n * 32 + 16 + tx] = make_uint2(pk2(o1.x, o1.y), pk2(o1.z, o1.w));
    }
  }
}

// ---------------- readout ----------------
__global__ __launch_bounds__(256) void k_readout(
    const float* __restrict__ h, const int* __restrict__ gid,
    const float* __restrict__ Wv, const float* __restrict__ bv,
    float* __restrict__ num, float* __restrict__ den) {
  __shared__ float wl[128];
  int base = blockIdx.x * 128;
  int t = threadIdx.x;

  {
    int n = base + (t >> 1);
    int half = t & 1;
    float s = 0.f;
    if (n < NN) {
      const float4* hp = (const float4*)(h + (size_t)n * D + half * 64);
      const float4* wp = (const float4*)(Wv + half * 64);
#pragma unroll
      for (int i = 0; i < 16; i++) {
        float4 a = hp[i], w = wp[i];
        s += a.x * w.x + a.y * w.y + a.z * w.z + a.w * w.w;
      }
    }
    s += __shfl_xor(s, 1);
    if (half == 0) {
      float wv = 0.f;
      if (n < NN) wv = 1.f / (1.f + expf(-(s + bv[0])));
      wl[t >> 1] = wv;
    }
  }
  __syncthreads();

  int c = t & 127;
  int rg = t >> 7;
  float acc = 0.f, wacc = 0.f;
  int cur = -1;
  for (int i = 0; i < 64; i++) {
    int nl = rg * 64 + i;
    int n = base + nl;
    if (n >= NN) break;
    int g = gid[n];
    if (g != cur) {
      if (cur >= 0) {
        unsafeAtomicAdd(&num[(size_t)cur * D + c], acc);
        if (c == 0) unsafeAtomicAdd(&den[cur], wacc);
      }
      cur = g; acc = 0.f; wacc = 0.f;
    }
    float wv = wl[nl];
    acc += wv * h[(size_t)n * D + c];
    if (c == 0) wacc += wv;
  }
  if (cur >= 0) {
    unsafeAtomicAdd(&num[(size_t)cur * D + c], acc);
    if (c == 0) unsafeAtomicAdd(&den[cur], wacc);
  }
}

// ---------------- final ----------------
__global__ void k_final(const float* __restrict__ num, const float* __restrict__ den,
                        const float* __restrict__ Wc, const float* __restrict__ bc,
                        float* __restrict__ out) {
  int t = threadIdx.x;
  int o = t & 15;
  for (int g = t >> 4; g < NG; g += 16) {
    float s = 0.f;
    const float* np = num + (size_t)g * D;
#pragma unroll 8
    for (int c = 0; c < D; c++) s += np[c] * Wc[c * NO + o];
    out[g * NO + o] = s / den[g] + bc[o];
  }
}

// ---------------- launch ----------------
extern "C" void kernel_launch(void* const* d_in, const int* in_sizes, int n_in,
                              void* d_out, int out_size, void* d_ws, size_t ws_size,
                              hipStream_t stream) {
  const float* x   = (const float*)d_in[0];
  const int*   src = (const int*)d_in[1];
  const int*   dst = (const int*)d_in[2];
  const int*   gid = (const int*)d_in[3];
  const float* W1  = (const float*)d_in[4];
  const float* b1  = (const float*)d_in[5];
  const float* W2  = (const float*)d_in[6];
  const float* b2  = (const float*)d_in[7];
  const float* W3  = (const float*)d_in[8];
  const float* b3  = (const float*)d_in[9];
  const float* Wv  = (const float*)d_in[10];
  const float* bv  = (const float*)d_in[11];
  const float* Wc  = (const float*)d_in[12];
  const float* bc  = (const float*)d_in[13];
  float* out = (float*)d_out;

  float* ws = (float*)d_ws;
  float* C       = ws;                       // 12,800,000 f : h/agg (in-place chain)
  uint2* hb      = (uint2*)(ws + 12800000);  // 25.6 MB : bf16 shadow [NN][128]
  uint2* ebuf    = (uint2*)(ws + 19200000);  // 12.8 MB : bucket-sorted (src,dst)
  int*   row_ptr = (int*)(ws + 22400000);    // 100,001
  int*   cnt     = (int*)(ws + 22500004);    // 100,000
  int*   eidx    = (int*)(ws + 22600004);    // 1,600,000
  float* inv     = ws + 24200004;            // 100,000
  float* num     = ws + 24300004;            // 16,384
  float* den     = ws + 24316388;            // 128 (contiguous after num)
  int*   bsum    = (int*)(ws + 24316516);    // 128
  int*   bsumG   = (int*)(ws + 24316644);    // 392
  int*   bbase   = (int*)(ws + 24317036);    // 392
  int*   bfill   = (int*)(ws + 24317428);    // 392

  // ---- bucketed CSR build
  k_zero<<<1, 256, 0, stream>>>((float*)bsumG, 98);  // 392 ints
  f_hist<<<G3, 256, 0, stream>>>(dst, bsumG);
  f_bscan<<<1, 512, 0, stream>>>(bsumG, bbase, bfill);
  f_scatter<<<G3, 256, 0, stream>>>(src, dst, bfill, ebuf);
  f_count<<<NBUK, 256, 0, stream>>>(ebuf, bbase, cnt);
  k_scan1<<<NB, 256, 0, stream>>>(cnt, bsum);
  k_scan2<<<1, 128, 0, stream>>>(bsum, row_ptr);
  k_scan3<<<NB, 256, 0, stream>>>(cnt, bsum, row_ptr, inv);
  f_fill<<<NBUK, 256, 0, stream>>>(ebuf, bbase, row_ptr, eidx);

  // ---- bf16 shadow of x
  k_conv<<<12500, 256, 0, stream>>>(x, hb);

  // ---- 3 layers (gather in-place-safe; gemm in-place, writes next bf16 shadow)
  k_gather<<<12500, 256, 0, stream>>>(hb, x, row_ptr, eidx, inv, C);
  k_gemm<1, 1><<<1563, 256, 0, stream>>>(C, W1, b1, C, hb);
  k_gather<<<12500, 256, 0, stream>>>(hb, C, row_ptr, eidx, inv, C);
  k_gemm<1, 1><<<1563, 256, 0, stream>>>(C, W2, b2, C, hb);
  k_gather<<<12500, 256, 0, stream>>>(hb, C, row_ptr, eidx, inv, C);
  k_gemm<0, 0><<<1563, 256, 0, stream>>>(C, W3, b3, C, nullptr);

  // ---- readout
  k_zero<<<17, 256, 0, stream>>>(num, 4128);  // num + den contiguous
  k_readout<<<782, 256, 0, stream>>>(C, gid, Wv, bv, num, den);
  k_final<<<1, 256, 0, stream>>>(num, den, Wc, bc, out);
}

// Round 6
// 528.133 us; speedup vs baseline: 15.8865x; 1.0005x over previous
//
#include <hip/hip_runtime.h>

#define NN 100000
#define NE 1600000
#define D  128
#define NG 128
#define NO 16
#define NB 98     // scan blocks: 98*1024 >= NN
#define NBUK 391  // dst>>8 buckets: 391*256 >= NN
#define G3 256    // blocks for hist/scatter; G3 * 6250 == NE

typedef unsigned short ushort_t;
typedef __attribute__((ext_vector_type(8))) short short8;
typedef __attribute__((ext_vector_type(4))) float f32x4;

__device__ inline unsigned short f2bf(float f) {  // RNE float->bf16
  unsigned u = __float_as_uint(f);
  unsigned r = u + 0x7fffu + ((u >> 16) & 1u);
  return (unsigned short)(r >> 16);
}
__device__ inline unsigned pk2(float a, float b) {
  return (unsigned)f2bf(a) | ((unsigned)f2bf(b) << 16);
}

// ---------------- utility ----------------
__global__ void k_zero(float* __restrict__ p, int n4) {
  int i = blockIdx.x * blockDim.x + threadIdx.x;
  float4 z = make_float4(0.f, 0.f, 0.f, 0.f);
  for (; i < n4; i += gridDim.x * blockDim.x) ((float4*)p)[i] = z;
}

// ---------------- bucketed CSR build ----------------
__global__ __launch_bounds__(256) void f_hist(const int* __restrict__ dst,
                                              int* __restrict__ bsumG) {
  __shared__ int h[NBUK];
  for (int i = threadIdx.x; i < NBUK; i += 256) h[i] = 0;
  __syncthreads();
  int lo = blockIdx.x * (NE / G3), hi = lo + (NE / G3);
  for (int e = lo + threadIdx.x; e < hi; e += 256) atomicAdd(&h[dst[e] >> 8], 1);
  __syncthreads();
  for (int i = threadIdx.x; i < NBUK; i += 256)
    if (h[i]) atomicAdd(&bsumG[i], h[i]);
}

__global__ __launch_bounds__(512) void f_bscan(const int* __restrict__ bsumG,
                                               int* __restrict__ bbase,
                                               int* __restrict__ bfill) {
  __shared__ int s[512];
  int t = threadIdx.x;
  int v = (t < NBUK) ? bsumG[t] : 0;
  s[t] = v;
  __syncthreads();
  for (int d = 1; d < 512; d <<= 1) {
    int x = (t >= d) ? s[t - d] : 0;
    __syncthreads();
    s[t] += x;
    __syncthreads();
  }
  if (t < NBUK) {
    int e = s[t] - v;
    bbase[t] = e;
    bfill[t] = e;
  }
  if (t == NBUK - 1) bbase[NBUK] = s[t];  // == NE
}

__global__ __launch_bounds__(256) void f_scatter(const int* __restrict__ src,
                                                 const int* __restrict__ dst,
                                                 int* __restrict__ bfill,
                                                 uint2* __restrict__ ebuf) {
  __shared__ int h[NBUK];
  __shared__ int base[NBUK];
  for (int i = threadIdx.x; i < NBUK; i += 256) h[i] = 0;
  __syncthreads();
  int lo = blockIdx.x * (NE / G3), hi = lo + (NE / G3);
  for (int e = lo + threadIdx.x; e < hi; e += 256) atomicAdd(&h[dst[e] >> 8], 1);
  __syncthreads();
  for (int i = threadIdx.x; i < NBUK; i += 256) {
    int c = h[i];
    base[i] = c ? atomicAdd(&bfill[i], c) : 0;
  }
  __syncthreads();
  for (int i = threadIdx.x; i < NBUK; i += 256) h[i] = 0;
  __syncthreads();
  for (int e = lo + threadIdx.x; e < hi; e += 256) {
    int d = dst[e];
    int b = d >> 8;
    int k = atomicAdd(&h[b], 1);
    ebuf[base[b] + k] = make_uint2((unsigned)src[e], (unsigned)d);
  }
}

__global__ __launch_bounds__(256) void f_count(const uint2* __restrict__ ebuf,
                                               const int* __restrict__ bbase,
                                               int* __restrict__ cnt) {
  __shared__ int c[256];
  int b = blockIdx.x;
  c[threadIdx.x] = 0;
  __syncthreads();
  int lo = bbase[b], hi = bbase[b + 1];
  for (int i = lo + threadIdx.x; i < hi; i += 256)
    atomicAdd(&c[ebuf[i].y & 255], 1);
  __syncthreads();
  int n = (b << 8) + threadIdx.x;
  if (n < NN) cnt[n] = c[threadIdx.x];
}

__global__ __launch_bounds__(256) void f_fill(const uint2* __restrict__ ebuf,
                                              const int* __restrict__ bbase,
                                              const int* __restrict__ row_ptr,
                                              int* __restrict__ eidx) {
  __shared__ int fl[256];
  __shared__ int rp[256];
  int b = blockIdx.x;
  int n = (b << 8) + threadIdx.x;
  fl[threadIdx.x] = 0;
  rp[threadIdx.x] = (n < NN) ? row_ptr[n] : 0;
  __syncthreads();
  int lo = bbase[b], hi = bbase[b + 1];
  for (int i = lo + threadIdx.x; i < hi; i += 256) {
    uint2 p = ebuf[i];
    int dl = p.y & 255;
    int k = atomicAdd(&fl[dl], 1);
    eidx[rp[dl] + k] = (int)p.x;
  }
}

// ---------------- 3-stage scan over cnt -> row_ptr, inv ----------------
__global__ __launch_bounds__(256) void k_scan1(const int* __restrict__ cnt,
                                               int* __restrict__ bsum) {
  int b = blockIdx.x, t = threadIdx.x;
  int i0 = b * 1024 + t * 4;
  int4 v = make_int4(0, 0, 0, 0);
  if (i0 < NN) v = *(const int4*)(cnt + i0);
  int s = v.x + v.y + v.z + v.w;
#pragma unroll
  for (int d = 1; d < 64; d <<= 1) s += __shfl_xor(s, d);
  __shared__ int ws[4];
  if ((t & 63) == 0) ws[t >> 6] = s;
  __syncthreads();
  if (t == 0) bsum[b] = ws[0] + ws[1] + ws[2] + ws[3];
}

__global__ __launch_bounds__(128) void k_scan2(int* __restrict__ bsum,
                                               int* __restrict__ row_ptr) {
  __shared__ int s[128];
  int t = threadIdx.x;
  int v = (t < NB) ? bsum[t] : 0;
  s[t] = v;
  __syncthreads();
#pragma unroll
  for (int d = 1; d < 128; d <<= 1) {
    int x = (t >= d) ? s[t - d] : 0;
    __syncthreads();
    s[t] += x;
    __syncthreads();
  }
  if (t < NB) bsum[t] = s[t] - v;
  if (t == 127) row_ptr[NN] = s[127];
}

__global__ __launch_bounds__(256) void k_scan3(const int* __restrict__ cnt,
                                               const int* __restrict__ bsum,
                                               int* __restrict__ row_ptr,
                                               float* __restrict__ inv) {
  int b = blockIdx.x, t = threadIdx.x;
  int i0 = b * 1024 + t * 4;
  int4 v = make_int4(0, 0, 0, 0);
  if (i0 < NN) v = *(const int4*)(cnt + i0);
  int tsum = v.x + v.y + v.z + v.w;
  int lane = t & 63;
  int incl = tsum;
#pragma unroll
  for (int d = 1; d < 64; d <<= 1) {
    int x = __shfl_up(incl, d);
    if (lane >= d) incl += x;
  }
  __shared__ int wsum[4];
  if (lane == 63) wsum[t >> 6] = incl;
  __syncthreads();
  int base = bsum[b] + incl - tsum;
  int w = t >> 6;
#pragma unroll
  for (int i = 0; i < 4; i++) base += (i < w) ? wsum[i] : 0;
  if (i0 < NN) {
    int e0 = base, e1 = e0 + v.x, e2 = e1 + v.y, e3 = e2 + v.z;
    *(int4*)(row_ptr + i0) = make_int4(e0, e1, e2, e3);
    float4 iv;
    iv.x = 1.f / (float)(v.x + 1);
    iv.y = 1.f / (float)(v.y + 1);
    iv.z = 1.f / (float)(v.z + 1);
    iv.w = 1.f / (float)(v.w + 1);
    *(float4*)(inv + i0) = iv;
  }
}

// ---------------- convert f32 -> bf16 shadow ----------------
__global__ void k_conv(const float* __restrict__ x, uint2* __restrict__ xb) {
  int i = blockIdx.x * 256 + threadIdx.x;
  if (i < NN * 32) {
    float4 v = ((const float4*)x)[i];
    xb[i] = make_uint2(pk2(v.x, v.y), pk2(v.z, v.w));
  }
}

// ---------------- W [128k][128n] f32 -> Wt hi/lo bf16 [n][k] ----------------
__global__ void k_wconv(const float* __restrict__ W, ushort_t* __restrict__ hi,
                        ushort_t* __restrict__ lo) {
  int idx = blockIdx.x * 256 + threadIdx.x;
  if (idx >= D * D) return;
  int k = idx >> 7, n = idx & 127;
  float w = W[idx];
  unsigned short h = f2bf(w);
  float hw = __uint_as_float((unsigned)h << 16);
  hi[n * D + k] = h;
  lo[n * D + k] = f2bf(w - hw);
}

// ---------------- gather: aggb[n] = bf16((sum_{u->n} hb[u] + hb[n]) * inv[n]) ----------------
__global__ __launch_bounds__(256) void k_gather(
    const uint2* __restrict__ hb, const int* __restrict__ rp,
    const int* __restrict__ eidx, const float* __restrict__ inv,
    uint2* __restrict__ aggb) {
  int t = blockIdx.x * 256 + threadIdx.x;
  int n = t >> 5;
  int l = t & 31;
  if (n >= NN) return;
  int s0 = rp[n], s1 = rp[n + 1];

  uint2 sq = hb[(size_t)n * 32 + l];  // self
  float4 a0, a1, a2, a3;
  a0.x = __uint_as_float(sq.x << 16);
  a0.y = __uint_as_float(sq.x & 0xffff0000u);
  a0.z = __uint_as_float(sq.y << 16);
  a0.w = __uint_as_float(sq.y & 0xffff0000u);
  a1 = make_float4(0.f, 0.f, 0.f, 0.f);
  a2 = make_float4(0.f, 0.f, 0.f, 0.f);
  a3 = make_float4(0.f, 0.f, 0.f, 0.f);

  int i = s0;
  for (; i + 8 <= s1; i += 8) {
    int u[8];
    uint2 q[8];
#pragma unroll
    for (int j = 0; j < 8; j++) u[j] = eidx[i + j];
#pragma unroll
    for (int j = 0; j < 8; j++) q[j] = hb[(size_t)u[j] * 32 + l];
#pragma unroll
    for (int j = 0; j < 8; j++) {
      float4* a = (j & 2) ? ((j & 1) ? &a3 : &a2) : ((j & 1) ? &a1 : &a0);
      a->x += __uint_as_float(q[j].x << 16);
      a->y += __uint_as_float(q[j].x & 0xffff0000u);
      a->z += __uint_as_float(q[j].y << 16);
      a->w += __uint_as_float(q[j].y & 0xffff0000u);
    }
  }
  for (; i + 4 <= s1; i += 4) {
    int u[4];
    uint2 q[4];
#pragma unroll
    for (int j = 0; j < 4; j++) u[j] = eidx[i + j];
#pragma unroll
    for (int j = 0; j < 4; j++) q[j] = hb[(size_t)u[j] * 32 + l];
#pragma unroll
    for (int j = 0; j < 4; j++) {
      float4* a = (j & 2) ? ((j & 1) ? &a3 : &a2) : ((j & 1) ? &a1 : &a0);
      a->x += __uint_as_float(q[j].x << 16);
      a->y += __uint_as_float(q[j].x & 0xffff0000u);
      a->z += __uint_as_float(q[j].y << 16);
      a->w += __uint_as_float(q[j].y & 0xffff0000u);
    }
  }
  for (; i < s1; i++) {
    uint2 q = hb[(size_t)eidx[i] * 32 + l];
    a0.x += __uint_as_float(q.x << 16);
    a0.y += __uint_as_float(q.x & 0xffff0000u);
    a0.z += __uint_as_float(q.y << 16);
    a0.w += __uint_as_float(q.y & 0xffff0000u);
  }

  float iv = inv[n];
  float rx = (a0.x + a1.x + a2.x + a3.x) * iv;
  float ry = (a0.y + a1.y + a2.y + a3.y) * iv;
  float rz = (a0.z + a1.z + a2.z + a3.z) * iv;
  float rw = (a0.w + a1.w + a2.w + a3.w) * iv;
  aggb[(size_t)n * 32 + l] = make_uint2(pk2(rx, ry), pk2(rz, rw));
}

// ---------------- MFMA GEMM: out = act(A @ (Whi+Wlo) + b) ----------------
// A bf16 [rows][128]; Wt hi/lo bf16 [n][k] (transposed). 4 waves/block, 16 rows/wave.
// mfma_f32_16x16x32_bf16: A-frag lane l: row l&15, k (l>>4)*8+i.
//                         B-frag lane l: col l&15, k (l>>4)*8+i.
//                         D: col l&15, row (l>>4)*4+r.
template <int RELU, int F32OUT>
__global__ __launch_bounds__(256) void k_mfma(
    const ushort_t* __restrict__ A, const ushort_t* __restrict__ Whi,
    const ushort_t* __restrict__ Wlo, const float* __restrict__ bias,
    ushort_t* __restrict__ outb, float* __restrict__ outf) {
  int t = threadIdx.x;
  int w = t >> 6;
  int l = t & 63;
  int m = l & 15;
  int seg = l >> 4;
  int wbase = blockIdx.x * 64 + w * 16;

  const ushort_t* arow = A + (size_t)(wbase + m) * D;
  short8 a[4];
#pragma unroll
  for (int kc = 0; kc < 4; kc++)
    a[kc] = *(const short8*)(arow + kc * 32 + seg * 8);

#pragma unroll
  for (int cb = 0; cb < 8; cb++) {
    int col = cb * 16 + m;
    const ushort_t* bh = Whi + (size_t)col * D + seg * 8;
    const ushort_t* bl = Wlo + (size_t)col * D + seg * 8;
    f32x4 acc = {0.f, 0.f, 0.f, 0.f};
#pragma unroll
    for (int kc = 0; kc < 4; kc++) {
      short8 bf = *(const short8*)(bh + kc * 32);
      acc = __builtin_amdgcn_mfma_f32_16x16x32_bf16(a[kc], bf, acc, 0, 0, 0);
    }
#pragma unroll
    for (int kc = 0; kc < 4; kc++) {
      short8 bf = *(const short8*)(bl + kc * 32);
      acc = __builtin_amdgcn_mfma_f32_16x16x32_bf16(a[kc], bf, acc, 0, 0, 0);
    }
    float bb = bias[col];
    int r0 = wbase + seg * 4;
#pragma unroll
    for (int r = 0; r < 4; r++) {
      int rr = r0 + r;
      if (rr < NN) {
        float v = acc[r] + bb;
        if (RELU) v = fmaxf(v, 0.f);
        if (F32OUT) outf[(size_t)rr * D + col] = v;
        else outb[(size_t)rr * D + col] = f2bf(v);
      }
    }
  }
}

// ---------------- readout ----------------
__global__ __launch_bounds__(256) void k_readout(
    const float* __restrict__ h, const int* __restrict__ gid,
    const float* __restrict__ Wv, const float* __restrict__ bv,
    float* __restrict__ num, float* __restrict__ den) {
  __shared__ float wl[128];
  int base = blockIdx.x * 128;
  int t = threadIdx.x;

  {
    int n = base + (t >> 1);
    int half = t & 1;
    float s = 0.f;
    if (n < NN) {
      const float4* hp = (const float4*)(h + (size_t)n * D + half * 64);
      const float4* wp = (const float4*)(Wv + half * 64);
#pragma unroll
      for (int i = 0; i < 16; i++) {
        float4 a = hp[i], w = wp[i];
        s += a.x * w.x + a.y * w.y + a.z * w.z + a.w * w.w;
      }
    }
    s += __shfl_xor(s, 1);
    if (half == 0) {
      float wv = 0.f;
      if (n < NN) wv = 1.f / (1.f + expf(-(s + bv[0])));
      wl[t >> 1] = wv;
    }
  }
  __syncthreads();

  int c = t & 127;
  int rg = t >> 7;
  float acc = 0.f, wacc = 0.f;
  int cur = -1;
  for (int i = 0; i < 64; i++) {
    int nl = rg * 64 + i;
    int n = base + nl;
    if (n >= NN) break;
    int g = gid[n];
    if (g != cur) {
      if (cur >= 0) {
        unsafeAtomicAdd(&num[(size_t)cur * D + c], acc);
        if (c == 0) unsafeAtomicAdd(&den[cur], wacc);
      }
      cur = g; acc = 0.f; wacc = 0.f;
    }
    float wv = wl[nl];
    acc += wv * h[(size_t)n * D + c];
    if (c == 0) wacc += wv;
  }
  if (cur >= 0) {
    unsafeAtomicAdd(&num[(size_t)cur * D + c], acc);
    if (c == 0) unsafeAtomicAdd(&den[cur], wacc);
  }
}

// ---------------- final ----------------
__global__ void k_final(const float* __restrict__ num, const float* __restrict__ den,
                        const float* __restrict__ Wc, const float* __restrict__ bc,
                        float* __restrict__ out) {
  int t = threadIdx.x;
  int o = t & 15;
  for (int g = t >> 4; g < NG; g += 16) {
    float s = 0.f;
    const float* np = num + (size_t)g * D;
#pragma unroll 8
    for (int c = 0; c < D; c++) s += np[c] * Wc[c * NO + o];
    out[g * NO + o] = s / den[g] + bc[o];
  }
}

// ---------------- launch ----------------
extern "C" void kernel_launch(void* const* d_in, const int* in_sizes, int n_in,
                              void* d_out, int out_size, void* d_ws, size_t ws_size,
                              hipStream_t stream) {
  const float* x   = (const float*)d_in[0];
  const int*   src = (const int*)d_in[1];
  const int*   dst = (const int*)d_in[2];
  const int*   gid = (const int*)d_in[3];
  const float* W1  = (const float*)d_in[4];
  const float* b1  = (const float*)d_in[5];
  const float* W2  = (const float*)d_in[6];
  const float* b2  = (const float*)d_in[7];
  const float* W3  = (const float*)d_in[8];
  const float* b3  = (const float*)d_in[9];
  const float* Wv  = (const float*)d_in[10];
  const float* bv  = (const float*)d_in[11];
  const float* Wc  = (const float*)d_in[12];
  const float* bc  = (const float*)d_in[13];
  float* out = (float*)d_out;

  float* ws = (float*)d_ws;
  // layout (floats). 100,032+ rows reserved for bf16 buffers (k_mfma reads to row 100,031).
  ushort_t* hb   = (ushort_t*)ws;                 // [12,820,000 ushorts] @ 0 .. 6,410,000
  ushort_t* aggb = (ushort_t*)(ws + 6410000);     // same size .. 12,820,000
  float* C       = ws + 12820000;                 // 12,800,000 f .. 25,620,000 (layer-3 f32 out)
  uint2* ebuf    = (uint2*)(ws + 12820000);       // 3,200,000 f (dead before C is written)
  int*   row_ptr = (int*)(ws + 25620000);         // 100,004
  int*   cnt     = (int*)(ws + 25720004);         // 100,000
  int*   eidx    = (int*)(ws + 25820004);         // 1,600,000
  float* inv     = ws + 27420004;                 // 100,000
  float* num     = ws + 27520004;                 // 16,384
  float* den     = ws + 27536388;                 // 128 (contiguous after num)
  int*   bsum    = (int*)(ws + 27536516);         // 128
  int*   bsumG   = (int*)(ws + 27536644);         // 392
  int*   bbase   = (int*)(ws + 27537036);         // 392
  int*   bfill   = (int*)(ws + 27537428);         // 392
  ushort_t* Wt   = (ushort_t*)(ws + 27537820);    // 6 x 16384 ushorts (hi/lo x 3)
  ushort_t* W1h = Wt, *W1l = Wt + 16384;
  ushort_t* W2h = Wt + 32768, *W2l = Wt + 49152;
  ushort_t* W3h = Wt + 65536, *W3l = Wt + 81920;

  // ---- bucketed CSR build
  k_zero<<<1, 256, 0, stream>>>((float*)bsumG, 98);  // 392 ints
  f_hist<<<G3, 256, 0, stream>>>(dst, bsumG);
  f_bscan<<<1, 512, 0, stream>>>(bsumG, bbase, bfill);
  f_scatter<<<G3, 256, 0, stream>>>(src, dst, bfill, ebuf);
  f_count<<<NBUK, 256, 0, stream>>>(ebuf, bbase, cnt);
  k_scan1<<<NB, 256, 0, stream>>>(cnt, bsum);
  k_scan2<<<1, 128, 0, stream>>>(bsum, row_ptr);
  k_scan3<<<NB, 256, 0, stream>>>(cnt, bsum, row_ptr, inv);
  f_fill<<<NBUK, 256, 0, stream>>>(ebuf, bbase, row_ptr, eidx);

  // ---- weight transforms + x shadow
  k_wconv<<<64, 256, 0, stream>>>(W1, W1h, W1l);
  k_wconv<<<64, 256, 0, stream>>>(W2, W2h, W2l);
  k_wconv<<<64, 256, 0, stream>>>(W3, W3h, W3l);
  k_conv<<<12500, 256, 0, stream>>>(x, (uint2*)hb);

  // ---- 3 layers, bf16 chain
  k_gather<<<12500, 256, 0, stream>>>((uint2*)hb, row_ptr, eidx, inv, (uint2*)aggb);
  k_mfma<1, 0><<<1563, 256, 0, stream>>>(aggb, W1h, W1l, b1, hb, nullptr);
  k_gather<<<12500, 256, 0, stream>>>((uint2*)hb, row_ptr, eidx, inv, (uint2*)aggb);
  k_mfma<1, 0><<<1563, 256, 0, stream>>>(aggb, W2h, W2l, b2, hb, nullptr);
  k_gather<<<12500, 256, 0, stream>>>((uint2*)hb, row_ptr, eidx, inv, (uint2*)aggb);
  k_mfma<0, 1><<<1563, 256, 0, stream>>>(aggb, W3h, W3l, b3, nullptr, C);

  // ---- readout
  k_zero<<<17, 256, 0, stream>>>(num, 4128);  // num + den contiguous
  k_readout<<<782, 256, 0, stream>>>(C, gid, Wv, bv, num, den);
  k_final<<<1, 256, 0, stream>>>(num, den, Wc, bc, out);
}

// Round 7
// 435.939 us; speedup vs baseline: 19.2463x; 1.2115x over previous
//
#include <hip/hip_runtime.h>

#define NN 100000
#define NE 1600000
#define D  128
#define NG 128
#define NO 16
#define NB 98     // scan blocks: 98*1024 >= NN
#define NBUK 391  // dst>>8 buckets: 391*256 >= NN
#define G3 256    // blocks for hist/scatter; G3 * 6250 == NE

typedef unsigned short ushort_t;
typedef __attribute__((ext_vector_type(8))) short short8;
typedef __attribute__((ext_vector_type(4))) float f32x4;

__device__ inline unsigned short f2bf(float f) {  // RNE float->bf16
  unsigned u = __float_as_uint(f);
  unsigned r = u + 0x7fffu + ((u >> 16) & 1u);
  return (unsigned short)(r >> 16);
}
__device__ inline unsigned pk2(float a, float b) {
  return (unsigned)f2bf(a) | ((unsigned)f2bf(b) << 16);
}

// ---------------- utility ----------------
__global__ void k_zero(float* __restrict__ p, int n4) {
  int i = blockIdx.x * blockDim.x + threadIdx.x;
  float4 z = make_float4(0.f, 0.f, 0.f, 0.f);
  for (; i < n4; i += gridDim.x * blockDim.x) ((float4*)p)[i] = z;
}

// ---------------- bucketed CSR build ----------------
__global__ __launch_bounds__(256) void f_hist(const int* __restrict__ dst,
                                              int* __restrict__ bsumG) {
  __shared__ int h[NBUK];
  for (int i = threadIdx.x; i < NBUK; i += 256) h[i] = 0;
  __syncthreads();
  int lo = blockIdx.x * (NE / G3), hi = lo + (NE / G3);
  for (int e = lo + threadIdx.x; e < hi; e += 256) atomicAdd(&h[dst[e] >> 8], 1);
  __syncthreads();
  for (int i = threadIdx.x; i < NBUK; i += 256)
    if (h[i]) atomicAdd(&bsumG[i], h[i]);
}

__global__ __launch_bounds__(512) void f_bscan(const int* __restrict__ bsumG,
                                               int* __restrict__ bbase,
                                               int* __restrict__ bfill) {
  __shared__ int s[512];
  int t = threadIdx.x;
  int v = (t < NBUK) ? bsumG[t] : 0;
  s[t] = v;
  __syncthreads();
  for (int d = 1; d < 512; d <<= 1) {
    int x = (t >= d) ? s[t - d] : 0;
    __syncthreads();
    s[t] += x;
    __syncthreads();
  }
  if (t < NBUK) {
    int e = s[t] - v;
    bbase[t] = e;
    bfill[t] = e;
  }
  if (t == NBUK - 1) bbase[NBUK] = s[t];  // == NE
}

// pack: src (low 20 bits) | dst-low-8 (bits 20..27)
__global__ __launch_bounds__(256) void f_scatter(const int* __restrict__ src,
                                                 const int* __restrict__ dst,
                                                 int* __restrict__ bfill,
                                                 unsigned* __restrict__ ebuf) {
  __shared__ int h[NBUK];
  __shared__ int base[NBUK];
  for (int i = threadIdx.x; i < NBUK; i += 256) h[i] = 0;
  __syncthreads();
  int lo = blockIdx.x * (NE / G3), hi = lo + (NE / G3);
  for (int e = lo + threadIdx.x; e < hi; e += 256) atomicAdd(&h[dst[e] >> 8], 1);
  __syncthreads();
  for (int i = threadIdx.x; i < NBUK; i += 256) {
    int c = h[i];
    base[i] = c ? atomicAdd(&bfill[i], c) : 0;
  }
  __syncthreads();
  for (int i = threadIdx.x; i < NBUK; i += 256) h[i] = 0;
  __syncthreads();
  for (int e = lo + threadIdx.x; e < hi; e += 256) {
    int d = dst[e];
    int b = d >> 8;
    int k = atomicAdd(&h[b], 1);
    ebuf[base[b] + k] = (unsigned)src[e] | ((unsigned)(d & 255) << 20);
  }
}

__global__ __launch_bounds__(256) void f_count(const unsigned* __restrict__ ebuf,
                                               const int* __restrict__ bbase,
                                               int* __restrict__ cnt) {
  __shared__ int c[256];
  int b = blockIdx.x;
  c[threadIdx.x] = 0;
  __syncthreads();
  int lo = bbase[b], hi = bbase[b + 1];
  for (int i = lo + threadIdx.x; i < hi; i += 256)
    atomicAdd(&c[ebuf[i] >> 20], 1);
  __syncthreads();
  int n = (b << 8) + threadIdx.x;
  if (n < NN) cnt[n] = c[threadIdx.x];
}

__global__ __launch_bounds__(256) void f_fill(const unsigned* __restrict__ ebuf,
                                              const int* __restrict__ bbase,
                                              const int* __restrict__ row_ptr,
                                              int* __restrict__ eidx) {
  __shared__ int fl[256];
  __shared__ int rp[256];
  int b = blockIdx.x;
  int n = (b << 8) + threadIdx.x;
  fl[threadIdx.x] = 0;
  rp[threadIdx.x] = (n < NN) ? row_ptr[n] : 0;
  __syncthreads();
  int lo = bbase[b], hi = bbase[b + 1];
  for (int i = lo + threadIdx.x; i < hi; i += 256) {
    unsigned p = ebuf[i];
    int dl = p >> 20;
    int k = atomicAdd(&fl[dl], 1);
    eidx[rp[dl] + k] = (int)(p & 0xFFFFFu);
  }
}

// ---------------- 3-stage scan over cnt -> row_ptr, inv ----------------
__global__ __launch_bounds__(256) void k_scan1(const int* __restrict__ cnt,
                                               int* __restrict__ bsum) {
  int b = blockIdx.x, t = threadIdx.x;
  int i0 = b * 1024 + t * 4;
  int4 v = make_int4(0, 0, 0, 0);
  if (i0 < NN) v = *(const int4*)(cnt + i0);
  int s = v.x + v.y + v.z + v.w;
#pragma unroll
  for (int d = 1; d < 64; d <<= 1) s += __shfl_xor(s, d);
  __shared__ int ws[4];
  if ((t & 63) == 0) ws[t >> 6] = s;
  __syncthreads();
  if (t == 0) bsum[b] = ws[0] + ws[1] + ws[2] + ws[3];
}

__global__ __launch_bounds__(128) void k_scan2(int* __restrict__ bsum,
                                               int* __restrict__ row_ptr) {
  __shared__ int s[128];
  int t = threadIdx.x;
  int v = (t < NB) ? bsum[t] : 0;
  s[t] = v;
  __syncthreads();
#pragma unroll
  for (int d = 1; d < 128; d <<= 1) {
    int x = (t >= d) ? s[t - d] : 0;
    __syncthreads();
    s[t] += x;
    __syncthreads();
  }
  if (t < NB) bsum[t] = s[t] - v;
  if (t == 127) row_ptr[NN] = s[127];
}

__global__ __launch_bounds__(256) void k_scan3(const int* __restrict__ cnt,
                                               const int* __restrict__ bsum,
                                               int* __restrict__ row_ptr,
                                               float* __restrict__ inv) {
  int b = blockIdx.x, t = threadIdx.x;
  int i0 = b * 1024 + t * 4;
  int4 v = make_int4(0, 0, 0, 0);
  if (i0 < NN) v = *(const int4*)(cnt + i0);
  int tsum = v.x + v.y + v.z + v.w;
  int lane = t & 63;
  int incl = tsum;
#pragma unroll
  for (int d = 1; d < 64; d <<= 1) {
    int x = __shfl_up(incl, d);
    if (lane >= d) incl += x;
  }
  __shared__ int wsum[4];
  if (lane == 63) wsum[t >> 6] = incl;
  __syncthreads();
  int base = bsum[b] + incl - tsum;
  int w = t >> 6;
#pragma unroll
  for (int i = 0; i < 4; i++) base += (i < w) ? wsum[i] : 0;
  if (i0 < NN) {
    int e0 = base, e1 = e0 + v.x, e2 = e1 + v.y, e3 = e2 + v.z;
    *(int4*)(row_ptr + i0) = make_int4(e0, e1, e2, e3);
    float4 iv;
    iv.x = 1.f / (float)(v.x + 1);
    iv.y = 1.f / (float)(v.y + 1);
    iv.z = 1.f / (float)(v.z + 1);
    iv.w = 1.f / (float)(v.w + 1);
    *(float4*)(inv + i0) = iv;
  }
}

// ---------------- convert f32 -> bf16 shadow ----------------
__global__ void k_conv(const float* __restrict__ x, uint2* __restrict__ xb) {
  int i = blockIdx.x * 256 + threadIdx.x;
  if (i < NN * 32) {
    float4 v = ((const float4*)x)[i];
    xb[i] = make_uint2(pk2(v.x, v.y), pk2(v.z, v.w));
  }
}

// ---------------- W [128k][128n] f32 -> Wt hi/lo bf16 [n][k] ----------------
__global__ void k_wconv(const float* __restrict__ W, ushort_t* __restrict__ hi,
                        ushort_t* __restrict__ lo) {
  int idx = blockIdx.x * 256 + threadIdx.x;
  if (idx >= D * D) return;
  int k = idx >> 7, n = idx & 127;
  float w = W[idx];
  unsigned short h = f2bf(w);
  float hw = __uint_as_float((unsigned)h << 16);
  hi[n * D + k] = h;
  lo[n * D + k] = f2bf(w - hw);
}

// ---------------- gather: aggb[n] = bf16((sum_{u->n} hb[u] + hb[n]) * inv[n]) ----------------
__global__ __launch_bounds__(256) void k_gather(
    const uint2* __restrict__ hb, const int* __restrict__ rp,
    const int* __restrict__ eidx, const float* __restrict__ inv,
    uint2* __restrict__ aggb) {
  int t = blockIdx.x * 256 + threadIdx.x;
  int n = t >> 5;
  int l = t & 31;
  if (n >= NN) return;
  int s0 = rp[n], s1 = rp[n + 1];

  uint2 sq = hb[(size_t)n * 32 + l];  // self
  float4 a0, a1, a2, a3;
  a0.x = __uint_as_float(sq.x << 16);
  a0.y = __uint_as_float(sq.x & 0xffff0000u);
  a0.z = __uint_as_float(sq.y << 16);
  a0.w = __uint_as_float(sq.y & 0xffff0000u);
  a1 = make_float4(0.f, 0.f, 0.f, 0.f);
  a2 = make_float4(0.f, 0.f, 0.f, 0.f);
  a3 = make_float4(0.f, 0.f, 0.f, 0.f);

  int i = s0;
  for (; i + 8 <= s1; i += 8) {
    int u[8];
    uint2 q[8];
#pragma unroll
    for (int j = 0; j < 8; j++) u[j] = eidx[i + j];
#pragma unroll
    for (int j = 0; j < 8; j++) q[j] = hb[(size_t)u[j] * 32 + l];
#pragma unroll
    for (int j = 0; j < 8; j++) {
      float4* a = (j & 2) ? ((j & 1) ? &a3 : &a2) : ((j & 1) ? &a1 : &a0);
      a->x += __uint_as_float(q[j].x << 16);
      a->y += __uint_as_float(q[j].x & 0xffff0000u);
      a->z += __uint_as_float(q[j].y << 16);
      a->w += __uint_as_float(q[j].y & 0xffff0000u);
    }
  }
  for (; i + 4 <= s1; i += 4) {
    int u[4];
    uint2 q[4];
#pragma unroll
    for (int j = 0; j < 4; j++) u[j] = eidx[i + j];
#pragma unroll
    for (int j = 0; j < 4; j++) q[j] = hb[(size_t)u[j] * 32 + l];
#pragma unroll
    for (int j = 0; j < 4; j++) {
      float4* a = (j & 2) ? ((j & 1) ? &a3 : &a2) : ((j & 1) ? &a1 : &a0);
      a->x += __uint_as_float(q[j].x << 16);
      a->y += __uint_as_float(q[j].x & 0xffff0000u);
      a->z += __uint_as_float(q[j].y << 16);
      a->w += __uint_as_float(q[j].y & 0xffff0000u);
    }
  }
  for (; i < s1; i++) {
    uint2 q = hb[(size_t)eidx[i] * 32 + l];
    a0.x += __uint_as_float(q.x << 16);
    a0.y += __uint_as_float(q.x & 0xffff0000u);
    a0.z += __uint_as_float(q.y << 16);
    a0.w += __uint_as_float(q.y & 0xffff0000u);
  }

  float iv = inv[n];
  float rx = (a0.x + a1.x + a2.x + a3.x) * iv;
  float ry = (a0.y + a1.y + a2.y + a3.y) * iv;
  float rz = (a0.z + a1.z + a2.z + a3.z) * iv;
  float rw = (a0.w + a1.w + a2.w + a3.w) * iv;
  aggb[(size_t)n * 32 + l] = make_uint2(pk2(rx, ry), pk2(rz, rw));
}

// ---------------- MFMA GEMM v2: out = act(A @ (Whi+Wlo) + b) ----------------
// Block = 256 thr (4 waves) x 64-row tile. B (hi+lo, wave's 32 cols) preloaded
// to regs ONCE; A tile staged to LDS with XOR slot-swizzle (slot ^= row&15) so
// ds_read_b128 fragments are conflict-free (16 rows same k-slot otherwise =
// 16-way stride-256B conflict, G4). 8 independent 8-deep MFMA chains per wave.
template <int RELU, int F32OUT>
__global__ __launch_bounds__(256) void k_mfma(
    const ushort_t* __restrict__ A, const ushort_t* __restrict__ Whi,
    const ushort_t* __restrict__ Wlo, const float* __restrict__ bias,
    ushort_t* __restrict__ outb, float* __restrict__ outf) {
  __shared__ ushort_t sA[64 * 128];  // 16 KB, slot-swizzled
  int t = threadIdx.x;
  int w = t >> 6;
  int l = t & 63;
  int m = l & 15;
  int seg = l >> 4;
  int R0 = blockIdx.x * 64;

  // ---- B preload (issue first: overlaps A staging). wave w: cols w*32..+31
  short8 Bh[2][4], Bl[2][4];
#pragma unroll
  for (int cb2 = 0; cb2 < 2; cb2++) {
    int col = (w * 2 + cb2) * 16 + m;
    const ushort_t* ph = Whi + (size_t)col * D + seg * 8;
    const ushort_t* pl = Wlo + (size_t)col * D + seg * 8;
#pragma unroll
    for (int kc = 0; kc < 4; kc++) {
      Bh[cb2][kc] = *(const short8*)(ph + kc * 32);
      Bl[cb2][kc] = *(const short8*)(pl + kc * 32);
    }
  }

  // ---- stage A tile: coalesced global read, swizzled LDS write (2-way, free)
#pragma unroll
  for (int r = 0; r < 4; r++) {
    int q = t + r * 256;   // 16B-unit index 0..1023
    int row = q >> 4;      // 0..63
    int slot = q & 15;
    float4 v = *(const float4*)(A + (size_t)(R0 + row) * D + slot * 8);
    int sl = slot ^ (row & 15);
    *(float4*)&sA[row * 128 + sl * 8] = v;
  }
  __syncthreads();

  // ---- A fragments: lane m = row, 16B at k-slot kc*4+seg (un-swizzle via ^m)
  short8 a[4][4];
#pragma unroll
  for (int rt = 0; rt < 4; rt++)
#pragma unroll
    for (int kc = 0; kc < 4; kc++) {
      int row = rt * 16 + m;
      int sl = (kc * 4 + seg) ^ m;
      a[rt][kc] = *(const short8*)&sA[row * 128 + sl * 8];
    }

  // ---- 8 independent chains of 8 MFMA; epilogue per chain
#pragma unroll
  for (int rt = 0; rt < 4; rt++) {
#pragma unroll
    for (int cb2 = 0; cb2 < 2; cb2++) {
      f32x4 acc = {0.f, 0.f, 0.f, 0.f};
#pragma unroll
      for (int kc = 0; kc < 4; kc++)
        acc = __builtin_amdgcn_mfma_f32_16x16x32_bf16(a[rt][kc], Bh[cb2][kc], acc, 0, 0, 0);
#pragma unroll
      for (int kc = 0; kc < 4; kc++)
        acc = __builtin_amdgcn_mfma_f32_16x16x32_bf16(a[rt][kc], Bl[cb2][kc], acc, 0, 0, 0);
      int col = (w * 2 + cb2) * 16 + m;
      float bb = bias[col];
      int r0 = R0 + rt * 16 + seg * 4;
#pragma unroll
      for (int r = 0; r < 4; r++) {
        int rr = r0 + r;
        if (rr < NN) {
          float v = acc[r] + bb;
          if (RELU) v = fmaxf(v, 0.f);
          if (F32OUT) outf[(size_t)rr * D + col] = v;
          else outb[(size_t)rr * D + col] = f2bf(v);
        }
      }
    }
  }
}

// ---------------- readout ----------------
__global__ __launch_bounds__(256) void k_readout(
    const float* __restrict__ h, const int* __restrict__ gid,
    const float* __restrict__ Wv, const float* __restrict__ bv,
    float* __restrict__ num, float* __restrict__ den) {
  __shared__ float wl[128];
  int base = blockIdx.x * 128;
  int t = threadIdx.x;

  {
    int n = base + (t >> 1);
    int half = t & 1;
    float s = 0.f;
    if (n < NN) {
      const float4* hp = (const float4*)(h + (size_t)n * D + half * 64);
      const float4* wp = (const float4*)(Wv + half * 64);
#pragma unroll
      for (int i = 0; i < 16; i++) {
        float4 a = hp[i], w = wp[i];
        s += a.x * w.x + a.y * w.y + a.z * w.z + a.w * w.w;
      }
    }
    s += __shfl_xor(s, 1);
    if (half == 0) {
      float wv = 0.f;
      if (n < NN) wv = 1.f / (1.f + expf(-(s + bv[0])));
      wl[t >> 1] = wv;
    }
  }
  __syncthreads();

  int c = t & 127;
  int rg = t >> 7;
  float acc = 0.f, wacc = 0.f;
  int cur = -1;
  for (int i = 0; i < 64; i++) {
    int nl = rg * 64 + i;
    int n = base + nl;
    if (n >= NN) break;
    int g = gid[n];
    if (g != cur) {
      if (cur >= 0) {
        unsafeAtomicAdd(&num[(size_t)cur * D + c], acc);
        if (c == 0) unsafeAtomicAdd(&den[cur], wacc);
      }
      cur = g; acc = 0.f; wacc = 0.f;
    }
    float wv = wl[nl];
    acc += wv * h[(size_t)n * D + c];
    if (c == 0) wacc += wv;
  }
  if (cur >= 0) {
    unsafeAtomicAdd(&num[(size_t)cur * D + c], acc);
    if (c == 0) unsafeAtomicAdd(&den[cur], wacc);
  }
}

// ---------------- final ----------------
__global__ void k_final(const float* __restrict__ num, const float* __restrict__ den,
                        const float* __restrict__ Wc, const float* __restrict__ bc,
                        float* __restrict__ out) {
  int t = threadIdx.x;
  int o = t & 15;
  for (int g = t >> 4; g < NG; g += 16) {
    float s = 0.f;
    const float* np = num + (size_t)g * D;
#pragma unroll 8
    for (int c = 0; c < D; c++) s += np[c] * Wc[c * NO + o];
    out[g * NO + o] = s / den[g] + bc[o];
  }
}

// ---------------- launch ----------------
extern "C" void kernel_launch(void* const* d_in, const int* in_sizes, int n_in,
                              void* d_out, int out_size, void* d_ws, size_t ws_size,
                              hipStream_t stream) {
  const float* x   = (const float*)d_in[0];
  const int*   src = (const int*)d_in[1];
  const int*   dst = (const int*)d_in[2];
  const int*   gid = (const int*)d_in[3];
  const float* W1  = (const float*)d_in[4];
  const float* b1  = (const float*)d_in[5];
  const float* W2  = (const float*)d_in[6];
  const float* b2  = (const float*)d_in[7];
  const float* W3  = (const float*)d_in[8];
  const float* b3  = (const float*)d_in[9];
  const float* Wv  = (const float*)d_in[10];
  const float* bv  = (const float*)d_in[11];
  const float* Wc  = (const float*)d_in[12];
  const float* bc  = (const float*)d_in[13];
  float* out = (float*)d_out;

  float* ws = (float*)d_ws;
  // layout (floats). bf16 buffers sized 100,156 rows (k_mfma over-reads to 100,031).
  ushort_t* hb   = (ushort_t*)ws;                 // 12,820,000 ushorts @ f0..6,410,000
  ushort_t* aggb = (ushort_t*)(ws + 6410000);     // 12,820,000 ushorts .. f12,820,000
  float* C       = ws + 12820000;                 // 12,800,000 f (layer-3 f32 out)
  unsigned* ebuf = (unsigned*)(ws + 12820000);    // 1,600,000 u (dead before C written)
  int*   row_ptr = (int*)(ws + 25620000);         // 100,004
  int*   cnt     = (int*)(ws + 25720004);         // 100,000
  int*   eidx    = (int*)(ws + 25820004);         // 1,600,000
  float* inv     = ws + 27420004;                 // 100,000
  float* num     = ws + 27520004;                 // 16,384
  float* den     = ws + 27536388;                 // 128 (contiguous after num)
  int*   bsum    = (int*)(ws + 27536516);         // 128
  int*   bsumG   = (int*)(ws + 27536644);         // 392
  int*   bbase   = (int*)(ws + 27537036);         // 392
  int*   bfill   = (int*)(ws + 27537428);         // 392
  ushort_t* Wt   = (ushort_t*)(ws + 27537820);    // 6 x 16384 ushorts
  ushort_t* W1h = Wt, *W1l = Wt + 16384;
  ushort_t* W2h = Wt + 32768, *W2l = Wt + 49152;
  ushort_t* W3h = Wt + 65536, *W3l = Wt + 81920;

  // ---- bucketed CSR build
  k_zero<<<1, 256, 0, stream>>>((float*)bsumG, 98);  // 392 ints
  f_hist<<<G3, 256, 0, stream>>>(dst, bsumG);
  f_bscan<<<1, 512, 0, stream>>>(bsumG, bbase, bfill);
  f_scatter<<<G3, 256, 0, stream>>>(src, dst, bfill, ebuf);
  f_count<<<NBUK, 256, 0, stream>>>(ebuf, bbase, cnt);
  k_scan1<<<NB, 256, 0, stream>>>(cnt, bsum);
  k_scan2<<<1, 128, 0, stream>>>(bsum, row_ptr);
  k_scan3<<<NB, 256, 0, stream>>>(cnt, bsum, row_ptr, inv);
  f_fill<<<NBUK, 256, 0, stream>>>(ebuf, bbase, row_ptr, eidx);

  // ---- weight transforms + x shadow
  k_wconv<<<64, 256, 0, stream>>>(W1, W1h, W1l);
  k_wconv<<<64, 256, 0, stream>>>(W2, W2h, W2l);
  k_wconv<<<64, 256, 0, stream>>>(W3, W3h, W3l);
  k_conv<<<12500, 256, 0, stream>>>(x, (uint2*)hb);

  // ---- 3 layers, bf16 chain
  k_gather<<<12500, 256, 0, stream>>>((uint2*)hb, row_ptr, eidx, inv, (uint2*)aggb);
  k_mfma<1, 0><<<1563, 256, 0, stream>>>(aggb, W1h, W1l, b1, hb, nullptr);
  k_gather<<<12500, 256, 0, stream>>>((uint2*)hb, row_ptr, eidx, inv, (uint2*)aggb);
  k_mfma<1, 0><<<1563, 256, 0, stream>>>(aggb, W2h, W2l, b2, hb, nullptr);
  k_gather<<<12500, 256, 0, stream>>>((uint2*)hb, row_ptr, eidx, inv, (uint2*)aggb);
  k_mfma<0, 1><<<1563, 256, 0, stream>>>(aggb, W3h, W3l, b3, nullptr, C);

  // ---- readout
  k_zero<<<17, 256, 0, stream>>>(num, 4128);  // num + den contiguous
  k_readout<<<782, 256, 0, stream>>>(C, gid, Wv, bv, num, den);
  k_final<<<1, 256, 0, stream>>>(num, den, Wc, bc, out);
}

// Round 8
// 392.083 us; speedup vs baseline: 21.3990x; 1.1119x over previous
//
#include <hip/hip_runtime.h>

#define NN 100000
#define NE 1600000
#define D  128
#define NG 128
#define NO 16
#define NBUK 391  // dst>>8 buckets: 391*256 >= NN
#define G3 256    // blocks for hist/scatter; G3 * 6250 == NE

typedef unsigned short ushort_t;
typedef __attribute__((ext_vector_type(8))) short short8;
typedef __attribute__((ext_vector_type(4))) float f32x4;

__device__ inline unsigned short f2bf(float f) {  // RNE float->bf16
  unsigned u = __float_as_uint(f);
  unsigned r = u + 0x7fffu + ((u >> 16) & 1u);
  return (unsigned short)(r >> 16);
}
__device__ inline unsigned pk2(float a, float b) {
  return (unsigned)f2bf(a) | ((unsigned)f2bf(b) << 16);
}
__device__ inline float bflo(unsigned q) { return __uint_as_float(q << 16); }
__device__ inline float bfhi(unsigned q) { return __uint_as_float(q & 0xffff0000u); }

// ---------------- utility ----------------
__global__ void k_zero(float* __restrict__ p, int n4) {
  int i = blockIdx.x * blockDim.x + threadIdx.x;
  float4 z = make_float4(0.f, 0.f, 0.f, 0.f);
  for (; i < n4; i += gridDim.x * blockDim.x) ((float4*)p)[i] = z;
}

// ---------------- bucketed CSR build ----------------
__global__ __launch_bounds__(256) void f_hist(const int* __restrict__ dst,
                                              int* __restrict__ bsumG) {
  __shared__ int h[NBUK];
  for (int i = threadIdx.x; i < NBUK; i += 256) h[i] = 0;
  __syncthreads();
  int lo = blockIdx.x * (NE / G3), hi = lo + (NE / G3);
  for (int e = lo + threadIdx.x; e < hi; e += 256) atomicAdd(&h[dst[e] >> 8], 1);
  __syncthreads();
  for (int i = threadIdx.x; i < NBUK; i += 256)
    if (h[i]) atomicAdd(&bsumG[i], h[i]);
}

__global__ __launch_bounds__(512) void f_bscan(const int* __restrict__ bsumG,
                                               int* __restrict__ bbase,
                                               int* __restrict__ bfill,
                                               int* __restrict__ row_ptr) {
  __shared__ int s[512];
  int t = threadIdx.x;
  int v = (t < NBUK) ? bsumG[t] : 0;
  s[t] = v;
  __syncthreads();
  for (int d = 1; d < 512; d <<= 1) {
    int x = (t >= d) ? s[t - d] : 0;
    __syncthreads();
    s[t] += x;
    __syncthreads();
  }
  if (t < NBUK) {
    int e = s[t] - v;
    bbase[t] = e;
    bfill[t] = e;
  }
  if (t == NBUK - 1) bbase[NBUK] = s[t];  // == NE
  if (t == 0) row_ptr[NN] = NE;
}

// pack: src (low 20 bits) | dst-low-8 (bits 20..27)
__global__ __launch_bounds__(256) void f_scatter(const int* __restrict__ src,
                                                 const int* __restrict__ dst,
                                                 int* __restrict__ bfill,
                                                 unsigned* __restrict__ ebuf) {
  __shared__ int h[NBUK];
  __shared__ int base[NBUK];
  for (int i = threadIdx.x; i < NBUK; i += 256) h[i] = 0;
  __syncthreads();
  int lo = blockIdx.x * (NE / G3), hi = lo + (NE / G3);
  for (int e = lo + threadIdx.x; e < hi; e += 256) atomicAdd(&h[dst[e] >> 8], 1);
  __syncthreads();
  for (int i = threadIdx.x; i < NBUK; i += 256) {
    int c = h[i];
    base[i] = c ? atomicAdd(&bfill[i], c) : 0;
  }
  __syncthreads();
  for (int i = threadIdx.x; i < NBUK; i += 256) h[i] = 0;
  __syncthreads();
  for (int e = lo + threadIdx.x; e < hi; e += 256) {
    int d = dst[e];
    int b = d >> 8;
    int k = atomicAdd(&h[b], 1);
    ebuf[base[b] + k] = (unsigned)src[e] | ((unsigned)(d & 255) << 20);
  }
}

// one block per bucket: count -> in-block scan -> row_ptr/inv -> CSR fill
__global__ __launch_bounds__(256) void f_csr(const unsigned* __restrict__ ebuf,
                                             const int* __restrict__ bbase,
                                             int* __restrict__ row_ptr,
                                             float* __restrict__ inv,
                                             int* __restrict__ eidx) {
  __shared__ int c[256];
  __shared__ int rp[256];
  __shared__ int wsum[4];
  int b = blockIdx.x;
  int t = threadIdx.x;
  c[t] = 0;
  __syncthreads();
  int lo = bbase[b], hi = bbase[b + 1];
  for (int i = lo + t; i < hi; i += 256) atomicAdd(&c[ebuf[i] >> 20], 1);
  __syncthreads();
  int cnt = c[t];
  // exclusive scan of c[0..255] (wave incl-scan + wave offsets)
  int lane = t & 63;
  int incl = cnt;
#pragma unroll
  for (int d = 1; d < 64; d <<= 1) {
    int x = __shfl_up(incl, d);
    if (lane >= d) incl += x;
  }
  if (lane == 63) wsum[t >> 6] = incl;
  __syncthreads();
  int excl = incl - cnt;
  int w = t >> 6;
#pragma unroll
  for (int i = 0; i < 4; i++) excl += (i < w) ? wsum[i] : 0;
  int rpv = bbase[b] + excl;
  rp[t] = rpv;
  int n = (b << 8) + t;
  if (n < NN) {
    row_ptr[n] = rpv;
    inv[n] = 1.f / (float)(cnt + 1);
  }
  c[t] = 0;  // reuse as fill counters (only this thread touched c[t])
  __syncthreads();
  for (int i = lo + t; i < hi; i += 256) {
    unsigned p = ebuf[i];
    int dl = p >> 20;
    int k = atomicAdd(&c[dl], 1);
    eidx[rp[dl] + k] = (int)(p & 0xFFFFFu);
  }
}

// ---------------- convert f32 -> bf16 shadow ----------------
__global__ void k_conv(const float* __restrict__ x, uint4* __restrict__ xb) {
  int i = blockIdx.x * 256 + threadIdx.x;  // uint4 index; NN*16 total
  if (i < NN * 16) {
    float4 a = ((const float4*)x)[2 * i];
    float4 b = ((const float4*)x)[2 * i + 1];
    uint4 o;
    o.x = pk2(a.x, a.y); o.y = pk2(a.z, a.w);
    o.z = pk2(b.x, b.y); o.w = pk2(b.z, b.w);
    xb[i] = o;
  }
}

// ---------------- W1/W2/W3 [128k][128n] f32 -> Wt hi/lo bf16 [n][k] ----------------
__global__ void k_wconv3(const float* __restrict__ W1, const float* __restrict__ W2,
                         const float* __restrict__ W3, ushort_t* __restrict__ Wt) {
  int idx = blockIdx.x * 256 + threadIdx.x;  // 0..49151
  if (idx >= 3 * D * D) return;
  int m = idx / (D * D);
  int r = idx - m * (D * D);
  const float* W = (m == 0) ? W1 : (m == 1) ? W2 : W3;
  ushort_t* hip = Wt + m * 2 * D * D;
  ushort_t* lop = hip + D * D;
  int k = r >> 7, n = r & 127;
  float w = W[r];
  unsigned short h = f2bf(w);
  float hw = __uint_as_float((unsigned)h << 16);
  hip[n * D + k] = h;
  lop[n * D + k] = f2bf(w - hw);
}

// ---------------- gather: aggb[n] = bf16((sum_{u->n} hb[u] + hb[n]) * inv[n]) ----------------
// 16 lanes per node, one uint4 (8 bf16) per lane; 8 row-loads in flight.
__global__ __launch_bounds__(256) void k_gather(
    const uint4* __restrict__ hb4, const int* __restrict__ rp,
    const int* __restrict__ eidx, const float* __restrict__ inv,
    uint4* __restrict__ aggb4) {
  int t = blockIdx.x * 256 + threadIdx.x;
  int n = t >> 4;
  int l = t & 15;
  if (n >= NN) return;
  int s0 = rp[n], s1 = rp[n + 1];

  uint4 sq = hb4[(size_t)n * 16 + l];  // self
  float A0 = bflo(sq.x), A1 = bfhi(sq.x), A2 = bflo(sq.y), A3 = bfhi(sq.y);
  float A4 = bflo(sq.z), A5 = bfhi(sq.z), A6 = bflo(sq.w), A7 = bfhi(sq.w);
  float B0 = 0, B1 = 0, B2 = 0, B3 = 0, B4 = 0, B5 = 0, B6 = 0, B7 = 0;

  int i = s0;
  for (; i + 8 <= s1; i += 8) {
    int u[8];
    uint4 q[8];
#pragma unroll
    for (int j = 0; j < 8; j++) u[j] = eidx[i + j];
#pragma unroll
    for (int j = 0; j < 8; j++) q[j] = hb4[(size_t)u[j] * 16 + l];
#pragma unroll
    for (int j = 0; j < 8; j += 2) {
      A0 += bflo(q[j].x); A1 += bfhi(q[j].x); A2 += bflo(q[j].y); A3 += bfhi(q[j].y);
      A4 += bflo(q[j].z); A5 += bfhi(q[j].z); A6 += bflo(q[j].w); A7 += bfhi(q[j].w);
      B0 += bflo(q[j + 1].x); B1 += bfhi(q[j + 1].x); B2 += bflo(q[j + 1].y); B3 += bfhi(q[j + 1].y);
      B4 += bflo(q[j + 1].z); B5 += bfhi(q[j + 1].z); B6 += bflo(q[j + 1].w); B7 += bfhi(q[j + 1].w);
    }
  }
  for (; i + 2 <= s1; i += 2) {
    uint4 qa = hb4[(size_t)eidx[i] * 16 + l];
    uint4 qb = hb4[(size_t)eidx[i + 1] * 16 + l];
    A0 += bflo(qa.x); A1 += bfhi(qa.x); A2 += bflo(qa.y); A3 += bfhi(qa.y);
    A4 += bflo(qa.z); A5 += bfhi(qa.z); A6 += bflo(qa.w); A7 += bfhi(qa.w);
    B0 += bflo(qb.x); B1 += bfhi(qb.x); B2 += bflo(qb.y); B3 += bfhi(qb.y);
    B4 += bflo(qb.z); B5 += bfhi(qb.z); B6 += bflo(qb.w); B7 += bfhi(qb.w);
  }
  if (i < s1) {
    uint4 q = hb4[(size_t)eidx[i] * 16 + l];
    A0 += bflo(q.x); A1 += bfhi(q.x); A2 += bflo(q.y); A3 += bfhi(q.y);
    A4 += bflo(q.z); A5 += bfhi(q.z); A6 += bflo(q.w); A7 += bfhi(q.w);
  }

  float iv = inv[n];
  uint4 o;
  o.x = pk2((A0 + B0) * iv, (A1 + B1) * iv);
  o.y = pk2((A2 + B2) * iv, (A3 + B3) * iv);
  o.z = pk2((A4 + B4) * iv, (A5 + B5) * iv);
  o.w = pk2((A6 + B6) * iv, (A7 + B7) * iv);
  aggb4[(size_t)n * 16 + l] = o;
}

// ---------------- MFMA GEMM: out = act(A @ (Whi+Wlo) + b) ----------------
// Block = 256 thr (4 waves) x 64-row tile. B (hi+lo) preloaded to regs; A tile
// staged to LDS with XOR slot-swizzle; 8 independent 8-deep MFMA chains/wave.
template <int RELU>
__global__ __launch_bounds__(256) void k_mfma(
    const ushort_t* __restrict__ A, const ushort_t* __restrict__ Whi,
    const ushort_t* __restrict__ Wlo, const float* __restrict__ bias,
    ushort_t* __restrict__ outb) {
  __shared__ ushort_t sA[64 * 128];  // 16 KB, slot-swizzled
  int t = threadIdx.x;
  int w = t >> 6;
  int l = t & 63;
  int m = l & 15;
  int seg = l >> 4;
  int R0 = blockIdx.x * 64;

  // B preload (issue first: overlaps A staging). wave w: cols w*32..+31
  short8 Bh[2][4], Bl[2][4];
#pragma unroll
  for (int cb2 = 0; cb2 < 2; cb2++) {
    int col = (w * 2 + cb2) * 16 + m;
    const ushort_t* ph = Whi + (size_t)col * D + seg * 8;
    const ushort_t* pl = Wlo + (size_t)col * D + seg * 8;
#pragma unroll
    for (int kc = 0; kc < 4; kc++) {
      Bh[cb2][kc] = *(const short8*)(ph + kc * 32);
      Bl[cb2][kc] = *(const short8*)(pl + kc * 32);
    }
  }

  // stage A tile: coalesced global read, swizzled LDS write
#pragma unroll
  for (int r = 0; r < 4; r++) {
    int q = t + r * 256;   // 16B-unit index 0..1023
    int row = q >> 4;      // 0..63
    int slot = q & 15;
    float4 v = *(const float4*)(A + (size_t)(R0 + row) * D + slot * 8);
    int sl = slot ^ (row & 15);
    *(float4*)&sA[row * 128 + sl * 8] = v;
  }
  __syncthreads();

  // A fragments
  short8 a[4][4];
#pragma unroll
  for (int rt = 0; rt < 4; rt++)
#pragma unroll
    for (int kc = 0; kc < 4; kc++) {
      int row = rt * 16 + m;
      int sl = (kc * 4 + seg) ^ m;
      a[rt][kc] = *(const short8*)&sA[row * 128 + sl * 8];
    }

#pragma unroll
  for (int rt = 0; rt < 4; rt++) {
#pragma unroll
    for (int cb2 = 0; cb2 < 2; cb2++) {
      f32x4 acc = {0.f, 0.f, 0.f, 0.f};
#pragma unroll
      for (int kc = 0; kc < 4; kc++)
        acc = __builtin_amdgcn_mfma_f32_16x16x32_bf16(a[rt][kc], Bh[cb2][kc], acc, 0, 0, 0);
#pragma unroll
      for (int kc = 0; kc < 4; kc++)
        acc = __builtin_amdgcn_mfma_f32_16x16x32_bf16(a[rt][kc], Bl[cb2][kc], acc, 0, 0, 0);
      int col = (w * 2 + cb2) * 16 + m;
      float bb = bias[col];
      int r0 = R0 + rt * 16 + seg * 4;
#pragma unroll
      for (int r = 0; r < 4; r++) {
        int rr = r0 + r;
        if (rr < NN) {
          float v = acc[r] + bb;
          if (RELU) v = fmaxf(v, 0.f);
          outb[(size_t)rr * D + col] = f2bf(v);
        }
      }
    }
  }
}

// ---------------- readout: w = sigmoid(h@Wv+bv); num[g] += w*h; den[g] += w ----
// 256 nodes per block, bf16 h. Gate: one node per thread (16-deep loads).
// Accum: 4 waves x 64 rows each, one row per 64-lane wave per iter, 4-deep prefetch.
__global__ __launch_bounds__(256) void k_readout(
    const uint4* __restrict__ hb4, const int* __restrict__ gid,
    const float* __restrict__ Wv, const float* __restrict__ bv,
    float* __restrict__ num, float* __restrict__ den) {
  __shared__ float wl[256];
  __shared__ int gl[256];
  __shared__ float sWv[128];
  int base = blockIdx.x * 256;
  int t = threadIdx.x;

  if (t < 128) sWv[t] = Wv[t];
  {
    int n = base + t;
    gl[t] = (n < NN) ? gid[n] : -1;
  }
  __syncthreads();

  // gate phase
  {
    int n = base + t;
    float s = 0.f;
    if (n < NN) {
      const uint4* row = hb4 + (size_t)n * 16;
#pragma unroll
      for (int h = 0; h < 2; h++) {
        uint4 q[8];
#pragma unroll
        for (int j = 0; j < 8; j++) q[j] = row[h * 8 + j];
#pragma unroll
        for (int j = 0; j < 8; j++) {
          const float* wv = &sWv[(h * 8 + j) * 8];
          s += bflo(q[j].x) * wv[0] + bfhi(q[j].x) * wv[1];
          s += bflo(q[j].y) * wv[2] + bfhi(q[j].y) * wv[3];
          s += bflo(q[j].z) * wv[4] + bfhi(q[j].z) * wv[5];
          s += bflo(q[j].w) * wv[6] + bfhi(q[j].w) * wv[7];
        }
      }
      wl[t] = 1.f / (1.f + expf(-(s + bv[0])));
    } else {
      wl[t] = 0.f;
    }
  }
  __syncthreads();

  // accumulation phase: wave (t>>6) handles rows grp*64..+63; lane = uint col
  int grp = t >> 6;
  int lane = t & 63;
  const unsigned* hbu = (const unsigned*)hb4;
  float a0 = 0.f, a1 = 0.f, wacc = 0.f;
  int cur = -1;
  for (int i0 = 0; i0 < 64; i0 += 4) {
    unsigned q[4];
#pragma unroll
    for (int j = 0; j < 4; j++) {
      int n = base + grp * 64 + i0 + j;
      q[j] = (n < NN) ? hbu[(size_t)n * 64 + lane] : 0u;
    }
#pragma unroll
    for (int j = 0; j < 4; j++) {
      int nl = grp * 64 + i0 + j;
      int g = gl[nl];
      if (g != cur) {
        if (cur >= 0) {
          unsafeAtomicAdd(&num[(size_t)cur * D + 2 * lane], a0);
          unsafeAtomicAdd(&num[(size_t)cur * D + 2 * lane + 1], a1);
          if (lane == 0) unsafeAtomicAdd(&den[cur], wacc);
        }
        cur = g; a0 = 0.f; a1 = 0.f; wacc = 0.f;
      }
      float wv = wl[nl];
      a0 += wv * bflo(q[j]);
      a1 += wv * bfhi(q[j]);
      wacc += wv;
    }
  }
  if (cur >= 0) {
    unsafeAtomicAdd(&num[(size_t)cur * D + 2 * lane], a0);
    unsafeAtomicAdd(&num[(size_t)cur * D + 2 * lane + 1], a1);
    if (lane == 0) unsafeAtomicAdd(&den[cur], wacc);
  }
}

// ---------------- final ----------------
__global__ void k_final(const float* __restrict__ num, const float* __restrict__ den,
                        const float* __restrict__ Wc, const float* __restrict__ bc,
                        float* __restrict__ out) {
  int t = threadIdx.x;
  int o = t & 15;
  for (int g = t >> 4; g < NG; g += 16) {
    float s = 0.f;
    const float* np = num + (size_t)g * D;
#pragma unroll 8
    for (int c = 0; c < D; c++) s += np[c] * Wc[c * NO + o];
    out[g * NO + o] = s / den[g] + bc[o];
  }
}

// ---------------- launch ----------------
extern "C" void kernel_launch(void* const* d_in, const int* in_sizes, int n_in,
                              void* d_out, int out_size, void* d_ws, size_t ws_size,
                              hipStream_t stream) {
  const float* x   = (const float*)d_in[0];
  const int*   src = (const int*)d_in[1];
  const int*   dst = (const int*)d_in[2];
  const int*   gid = (const int*)d_in[3];
  const float* W1  = (const float*)d_in[4];
  const float* b1  = (const float*)d_in[5];
  const float* W2  = (const float*)d_in[6];
  const float* b2  = (const float*)d_in[7];
  const float* W3  = (const float*)d_in[8];
  const float* b3  = (const float*)d_in[9];
  const float* Wv  = (const float*)d_in[10];
  const float* bv  = (const float*)d_in[11];
  const float* Wc  = (const float*)d_in[12];
  const float* bc  = (const float*)d_in[13];
  float* out = (float*)d_out;

  float* ws = (float*)d_ws;
  // bf16 buffers sized 100,156 rows (k_mfma staging over-reads to row 100,031)
  ushort_t* hb   = (ushort_t*)ws;                 // 12,820,000 us @ f0..6,410,000
  ushort_t* aggb = (ushort_t*)(ws + 6410000);     // .. f12,820,000
  unsigned* ebuf = (unsigned*)(ws + 12820000);    // 1,600,000 u
  int*   row_ptr = (int*)(ws + 14420000);         // 100,004
  int*   eidx    = (int*)(ws + 14520004);         // 1,600,000
  float* inv     = ws + 16120004;                 // 100,000
  float* num     = ws + 16220004;                 // 16,384
  float* den     = ws + 16236388;                 // 128 (contiguous after num)
  int*   bsumG   = (int*)(ws + 16236516);         // 392
  int*   bbase   = (int*)(ws + 16236908);         // 392
  int*   bfill   = (int*)(ws + 16237300);         // 392
  ushort_t* Wt   = (ushort_t*)(ws + 16237696);    // 98,304 us (16B-aligned)
  ushort_t* W1h = Wt,          *W1l = Wt + 16384;
  ushort_t* W2h = Wt + 32768,  *W2l = Wt + 49152;
  ushort_t* W3h = Wt + 65536,  *W3l = Wt + 81920;

  // ---- bucketed CSR build (5 kernels)
  k_zero<<<1, 256, 0, stream>>>((float*)bsumG, 98);  // 392 ints
  f_hist<<<G3, 256, 0, stream>>>(dst, bsumG);
  f_bscan<<<1, 512, 0, stream>>>(bsumG, bbase, bfill, row_ptr);
  f_scatter<<<G3, 256, 0, stream>>>(src, dst, bfill, ebuf);
  f_csr<<<NBUK, 256, 0, stream>>>(ebuf, bbase, row_ptr, inv, eidx);

  // ---- weight transforms + x shadow
  k_wconv3<<<192, 256, 0, stream>>>(W1, W2, W3, Wt);
  k_conv<<<6250, 256, 0, stream>>>(x, (uint4*)hb);

  // ---- 3 layers, bf16 chain (layer 3 writes hb in place of old shadow)
  k_gather<<<6250, 256, 0, stream>>>((uint4*)hb, row_ptr, eidx, inv, (uint4*)aggb);
  k_mfma<1><<<1563, 256, 0, stream>>>(aggb, W1h, W1l, b1, hb);
  k_gather<<<6250, 256, 0, stream>>>((uint4*)hb, row_ptr, eidx, inv, (uint4*)aggb);
  k_mfma<1><<<1563, 256, 0, stream>>>(aggb, W2h, W2l, b2, hb);
  k_gather<<<6250, 256, 0, stream>>>((uint4*)hb, row_ptr, eidx, inv, (uint4*)aggb);
  k_mfma<0><<<1563, 256, 0, stream>>>(aggb, W3h, W3l, b3, hb);

  // ---- readout
  k_zero<<<17, 256, 0, stream>>>(num, 4128);  // num + den contiguous
  k_readout<<<391, 256, 0, stream>>>((uint4*)hb, gid, Wv, bv, num, den);
  k_final<<<1, 256, 0, stream>>>(num, den, Wc, bc, out);
}